// Round 17
// baseline (568.742 us; speedup 1.0000x reference)
//
#include <hip/hip_runtime.h>
#include <math.h>

#define N_ATOMS 50000
#define E_EDGES 100000
#define B_G     50
#define M_M     50
#define NPG     1000
#define DIN     32
#define H1C     32
#define H2C     64
#define DEC     16
#define AAF     95
#define G_DIM   128
#define K_ST    3
#define T_L     6
#define EA_E    98
#define XDIM    159          // H2 + AAF
#define NS      21           // K + T*K weight slices
#define MPAD    64           // M padded for regular tiling
#define GP      132          // G_DIM padded
#define XP      164          // XDIM padded for rc_gemm rows

typedef __attribute__((ext_vector_type(8))) short bf16x8;
typedef __attribute__((ext_vector_type(4))) float f32x4;

__device__ __forceinline__ short f2bf(float f) {
    unsigned int u = __float_as_uint(f);
    unsigned int r = (u + 0x7FFFu + ((u >> 16) & 1u)) >> 16;   // RNE
    return (short)r;
}
__device__ __forceinline__ float bf2f(short b) {
    return __uint_as_float(((unsigned int)(unsigned short)b) << 16);
}

__device__ __forceinline__ void f4fma(float4& d, float s, const float4& v) {
    d.x += s * v.x; d.y += s * v.y; d.z += s * v.z; d.w += s * v.w;
}
__device__ __forceinline__ void f4add(float4& d, const float4& v) {
    d.x += v.x; d.y += v.y; d.z += v.z; d.w += v.w;
}
__device__ __forceinline__ void f4relu(float4& d) {
    d.x = fmaxf(d.x, 0.f); d.y = fmaxf(d.y, 0.f);
    d.z = fmaxf(d.z, 0.f); d.w = fmaxf(d.w, 0.f);
}

// ---------------------------------------------------------------------------
// CSR build: degree count -> exclusive scan (1024-wide) -> bucket fill
// ---------------------------------------------------------------------------
__global__ __launch_bounds__(256) void deg_count(const int* __restrict__ eidx,
                                                 int* __restrict__ deg)
{
    int e = blockIdx.x * 256 + threadIdx.x;
    if (e >= E_EDGES) return;
    atomicAdd(&deg[eidx[E_EDGES + e]], 1);
}

__global__ __launch_bounds__(1024) void scan_kernel(int* __restrict__ deg_off)
{
    __shared__ int part[1024];
    int tid = threadIdx.x;
    const int SEG = (N_ATOMS + 1023) / 1024;   // 49
    int lo = tid * SEG;
    int hi = lo + SEG; if (hi > N_ATOMS) hi = N_ATOMS;
    int s = 0;
    for (int n = lo; n < hi; ++n) s += deg_off[n];
    part[tid] = s;
    __syncthreads();
    for (int off = 1; off < 1024; off <<= 1) {
        int v = part[tid];
        int add = (tid >= off) ? part[tid - off] : 0;
        __syncthreads();
        part[tid] = v + add;
        __syncthreads();
    }
    int run = (tid == 0) ? 0 : part[tid - 1];
    for (int n = lo; n < hi; ++n) {
        int d = deg_off[n];
        deg_off[n] = run;
        run += d;
    }
    if (tid == 1023) deg_off[N_ATOMS] = run;
}

__global__ __launch_bounds__(256) void fill_order(const int* __restrict__ eidx,
                                                  const int* __restrict__ off,
                                                  int* __restrict__ cursor,
                                                  int* __restrict__ order)
{
    int e = blockIdx.x * 256 + threadIdx.x;
    if (e >= E_EDGES) return;
    int d = eidx[E_EDGES + e];
    int pos = atomicAdd(&cursor[d], 1);
    order[off[d] + pos] = e;
}

// ---------------------------------------------------------------------------
// MFMA edge message kernel (R16, verified absmax 9.5e-7).
// ---------------------------------------------------------------------------
template<int FIN, int FOUT>
__global__ __launch_bounds__(256, 2) void edge_msg_mfma(
    const float* __restrict__ h, const float* __restrict__ ea,
    const int* __restrict__ eidx, const float* __restrict__ We,
    const float* __restrict__ be, float* __restrict__ msg)
{
    static_assert(FIN == 32, "K mapping assumes FIN==32");
    constexpr int K0  = DEC * FIN;        // 512
    constexpr int KS  = (K0 + FIN) / 32;  // 17
    constexpr int WTP = 552;
    constexpr int NT  = FOUT / 16;
    __shared__ short Wt[FOUT][WTP];
    __shared__ short hA[64][40];
    __shared__ short eaA[64][16];
    int tid = threadIdx.x;
    int ebase = blockIdx.x * 64;

    for (int i = tid; i < DEC * FIN * FOUT; i += 256) {
        int o  = i % FOUT;
        int fk = i / FOUT;
        Wt[o][fk] = f2bf(We[i]);
    }
    for (int i = tid; i < FIN * FOUT; i += 256) {
        int o = i % FOUT, ff = i / FOUT;
        Wt[o][K0 + ff] = f2bf(be[i]);
    }
    for (int i = tid; i < 64 * FIN; i += 256) {
        int r = i / FIN, f = i % FIN;
        int e = ebase + r; int es = (e < E_EDGES) ? e : 0;
        int s = eidx[es];
        hA[r][f] = f2bf(h[(size_t)s * FIN + f]);
    }
    for (int i = tid; i < 64 * DEC; i += 256) {
        int r = i / DEC, d = i % DEC;
        int e = ebase + r; int es = (e < E_EDGES) ? e : 0;
        eaA[r][d] = f2bf(ea[(size_t)es * DEC + d]);
    }
    __syncthreads();

    int lane = tid & 63;
    int wave = tid >> 6;
    int l16  = lane & 15;
    int quad = lane >> 4;

    float hf[8];
    {
        const short* hp = &hA[wave * 16 + l16][quad * 8];
        #pragma unroll
        for (int j = 0; j < 8; ++j) hf[j] = bf2f(hp[j]);
    }
    float eaf[16];
    {
        const short* ep = &eaA[wave * 16 + l16][0];
        #pragma unroll
        for (int d = 0; d < 16; ++d) eaf[d] = bf2f(ep[d]);
    }

    f32x4 acc[NT];
    #pragma unroll
    for (int nt = 0; nt < NT; ++nt) acc[nt] = (f32x4){0.f, 0.f, 0.f, 0.f};

    #pragma unroll
    for (int ks = 0; ks < KS; ++ks) {
        float fac = (ks < DEC) ? eaf[ks] : 1.0f;
        bf16x8 a;
        #pragma unroll
        for (int j = 0; j < 8; ++j) a[j] = f2bf(fac * hf[j]);
        #pragma unroll
        for (int nt = 0; nt < NT; ++nt) {
            const bf16x8 b = *(const bf16x8*)&Wt[nt * 16 + l16][ks * 32 + quad * 8];
            acc[nt] = __builtin_amdgcn_mfma_f32_16x16x32_bf16(a, b, acc[nt], 0, 0, 0);
        }
    }
    #pragma unroll
    for (int nt = 0; nt < NT; ++nt) {
        #pragma unroll
        for (int r = 0; r < 4; ++r) {
            int e = ebase + wave * 16 + quad * 4 + r;
            if (e < E_EDGES)
                msg[(size_t)e * FOUT + nt * 16 + l16] = acc[nt][r];
        }
    }
}

// ---------------------------------------------------------------------------
// Gather + node update fused
// ---------------------------------------------------------------------------
template<int FIN, int FOUT>
__global__ __launch_bounds__(256) void gather_update(
    const float* __restrict__ msg, const int* __restrict__ off,
    const int* __restrict__ order, const float* __restrict__ hin,
    const float* __restrict__ root, const float* __restrict__ bias,
    float* __restrict__ hout)
{
    constexpr int NPB = 256 / FOUT;
    __shared__ float rlds[FIN][FOUT];
    __shared__ float hlds[NPB][FIN];
    int tid = threadIdx.x;
    for (int i = tid; i < FIN * FOUT / 4; i += 256) {
        *(float4*)&rlds[0][i * 4] = *(const float4*)(root + i * 4);
    }
    int nb = blockIdx.x * NPB;
    for (int i = tid; i < NPB * FIN; i += 256) {
        int ln = i / FIN, f = i % FIN;
        int n = nb + ln;
        hlds[ln][f] = (n < N_ATOMS) ? hin[(size_t)n * FIN + f] : 0.f;
    }
    __syncthreads();

    int ln = tid / FOUT, o = tid % FOUT;
    int n = nb + ln;
    if (n >= N_ATOMS) return;
    float acc = bias[o];
    #pragma unroll 8
    for (int f = 0; f < FIN; ++f) acc += hlds[ln][f] * rlds[f][o];
    int j0 = off[n], j1 = off[n + 1];
    for (int j = j0; j < j1; ++j) {
        int e = order[j];
        acc += msg[(size_t)e * FOUT + o];
    }
    hout[(size_t)n * FOUT + o] = fmaxf(acc, 0.f);
}

// ---------------------------------------------------------------------------
// Atom attention: atom_score then atom_aggregate (softmax fused in-block)
// ---------------------------------------------------------------------------
__global__ __launch_bounds__(256) void atom_score(
    const float* __restrict__ h2, const float* __restrict__ wa,
    const float* __restrict__ ba, float* __restrict__ sc)
{
    __shared__ float hl[128][65];
    int nb = blockIdx.x * 128;
    int tid = threadIdx.x;
    for (int i = tid; i < 128 * 16; i += 256) {
        int r = i >> 4, c4 = i & 15;
        int n = nb + r;
        float4 v = (n < N_ATOMS) ? *(const float4*)(h2 + (size_t)n * H2C + c4 * 4)
                                 : make_float4(0.f, 0.f, 0.f, 0.f);
        *(float4*)&hl[r][c4 * 4] = v;
    }
    __syncthreads();
    if (tid < 128) {
        int n = nb + tid;
        if (n < N_ATOMS) {
            float sv = ba[0];
            #pragma unroll 8
            for (int o = 0; o < H2C; ++o) sv += hl[tid][o] * wa[o];
            sc[n] = sv;
        }
    }
}

__global__ __launch_bounds__(256) void atom_aggregate(
    const float* __restrict__ h2, const float* __restrict__ sc,
    const int* __restrict__ labels, const float* __restrict__ aaf,
    float* __restrict__ h_aa)
{
    int bx = blockIdx.x, tid = threadIdx.x;
    if (bx < 2 * B_G) {
        __shared__ float aa8[8][M_M][32];   // 51.2 KB
        __shared__ float red[256];
        int b = bx >> 1, half = bx & 1;
        int g = tid >> 5, o = tid & 31;
        const float* sb = sc + (size_t)b * NPG;
        float lmax = -1e30f;
        for (int n = tid; n < NPG; n += 256) lmax = fmaxf(lmax, sb[n]);
        red[tid] = lmax;
        __syncthreads();
        for (int off = 128; off > 0; off >>= 1) {
            if (tid < off) red[tid] = fmaxf(red[tid], red[tid + off]);
            __syncthreads();
        }
        float mx = red[0];
        __syncthreads();
        float lsum = 0.f;
        for (int n = tid; n < NPG; n += 256) lsum += expf(sb[n] - mx);
        red[tid] = lsum;
        __syncthreads();
        for (int off = 128; off > 0; off >>= 1) {
            if (tid < off) red[tid] += red[tid + off];
            __syncthreads();
        }
        float inv = 1.f / red[0];
        __syncthreads();
        for (int i = tid; i < 8 * M_M * 32; i += 256) ((float*)aa8)[i] = 0.f;
        __syncthreads();
        const float* hb = h2 + (size_t)b * NPG * H2C + half * 32;
        for (int n = g; n < NPG; n += 8) {
            int lbl = labels[b * NPG + n];
            float w = expf(sb[n] - mx) * inv;
            float hvv = hb[(size_t)n * H2C + o];
            aa8[g][lbl][o] += hvv * w;
        }
        __syncthreads();
        float* ob = h_aa + (size_t)b * M_M * XDIM + half * 32;
        for (int i = tid; i < M_M * 32; i += 256) {
            int m = i >> 5, oo = i & 31;
            float v = 0.f;
            #pragma unroll
            for (int gg = 0; gg < 8; ++gg) v += aa8[gg][m][oo];
            ob[m * XDIM + oo] = v;
        }
    } else {
        int b = bx - 2 * B_G;
        const float* ab = aaf + (size_t)b * M_M * AAF;
        float* ob = h_aa + (size_t)b * M_M * XDIM + H2C;
        for (int i = tid; i < M_M * AAF; i += 256) {
            int m = i / AAF, j = i - m * AAF;
            ob[m * XDIM + j] = ab[i];
        }
    }
}

// ---------------------------------------------------------------------------
// Amino-graph gcn_norm + dst-sorted CSR build (tiny, 1 block)
// ---------------------------------------------------------------------------
__global__ void aa_norm_kernel(const int* __restrict__ aei,
                               int* __restrict__ aa_off,
                               int* __restrict__ aa_src,
                               float* __restrict__ aa_nrm)
{
    __shared__ int   sdeg[M_M];
    __shared__ int   scur[M_M];
    __shared__ float sdinv[M_M];
    __shared__ int   soff[M_M + 1];
    int tid = threadIdx.x;
    if (tid < M_M) { sdeg[tid] = 0; scur[tid] = 0; }
    __syncthreads();
    if (tid < EA_E) atomicAdd(&sdeg[aei[EA_E + tid]], 1);
    __syncthreads();
    if (tid < M_M) {
        float dv = (float)sdeg[tid];
        sdinv[tid] = (dv > 0.f) ? (1.f / sqrtf(fmaxf(dv, 1.f))) : 0.f;
    }
    __syncthreads();
    if (tid == 0) {
        soff[0] = 0;
        for (int m = 0; m < M_M; ++m) soff[m + 1] = soff[m] + sdeg[m];
    }
    __syncthreads();
    if (tid < EA_E) {
        int ss = aei[tid], dd = aei[EA_E + tid];
        int pos = atomicAdd(&scur[dd], 1);
        int idx = soff[dd] + pos;
        aa_src[idx] = ss;
        aa_nrm[idx] = sdinv[ss] * sdinv[dd];
    }
    if (tid < M_M + 1) aa_off[tid] = soff[tid];
}

// ---------------------------------------------------------------------------
// Batched root GEMM, arma-style 4x8 tile. x0 in padded-row LDS (XP=164).
// ---------------------------------------------------------------------------
__global__ __launch_bounds__(256) void rc_gemm(
    const float* __restrict__ h_aa, const float* __restrict__ init_w,
    const float* __restrict__ root_w, float* __restrict__ RC)
{
    __shared__ float x0[MPAD][XP];   // 42 KB
    int b = blockIdx.x / NS, s = blockIdx.x % NS;
    int tid = threadIdx.x;
    int oi = tid & 15, mi = tid >> 4;
    int ob = oi * 8;
    const float* xb = h_aa + (size_t)b * M_M * XDIM;
    for (int i = tid; i < MPAD * XP; i += 256) {
        int m = i / XP, f = i - m * XP;
        x0[m][f] = (m < M_M && f < XDIM) ? xb[m * XDIM + f] : 0.f;
    }
    __syncthreads();
    const float* W = (s < K_ST) ? (init_w + (size_t)s * XDIM * G_DIM)
                                : (root_w + (size_t)(s - K_ST) * XDIM * G_DIM);
    float4 acc[4][2];
    #pragma unroll
    for (int r = 0; r < 4; ++r) {
        acc[r][0] = make_float4(0.f,0.f,0.f,0.f);
        acc[r][1] = make_float4(0.f,0.f,0.f,0.f);
    }
    int p = 0;
    for (; p + 4 <= XDIM; p += 4) {
        float4 wv[4][2];
        #pragma unroll
        for (int q = 0; q < 4; ++q) {
            const float* wr = W + (size_t)(p + q) * G_DIM + ob;
            wv[q][0] = *(const float4*)wr;
            wv[q][1] = *(const float4*)(wr + 4);
        }
        #pragma unroll
        for (int r = 0; r < 4; ++r) {
            float4 xv = *(const float4*)&x0[mi * 4 + r][p];
            #pragma unroll
            for (int hh = 0; hh < 2; ++hh) {
                f4fma(acc[r][hh], xv.x, wv[0][hh]);
                f4fma(acc[r][hh], xv.y, wv[1][hh]);
                f4fma(acc[r][hh], xv.z, wv[2][hh]);
                f4fma(acc[r][hh], xv.w, wv[3][hh]);
            }
        }
    }
    for (; p < XDIM; ++p) {
        const float* wr = W + (size_t)p * G_DIM + ob;
        float4 w0 = *(const float4*)wr;
        float4 w1 = *(const float4*)(wr + 4);
        #pragma unroll
        for (int r = 0; r < 4; ++r) {
            float xv = x0[mi * 4 + r][p];
            f4fma(acc[r][0], xv, w0);
            f4fma(acc[r][1], xv, w1);
        }
    }
    float* op = RC + ((size_t)(b * NS + s)) * M_M * G_DIM;
    #pragma unroll
    for (int r = 0; r < 4; ++r) {
        int m = mi * 4 + r;
        if (m < M_M) {
            float* pp = op + (size_t)m * G_DIM + ob;
            *(float4*)pp       = acc[r][0];
            *(float4*)(pp + 4) = acc[r][1];
        }
    }
}

// ---------------------------------------------------------------------------
// ARMA recurrence: one block per (b,k). 512 threads, 2x8 per-thread tile —
// grid is fixed at 150 blocks (<1/CU), so 8 waves/block = 2 waves/SIMD is the
// only latency-hiding lever (R16: 4 waves = 1/SIMD -> W-load latency-bound,
// VALUBusy 12%).
// ---------------------------------------------------------------------------
__global__ __launch_bounds__(512) void arma_iter(
    const float* __restrict__ RC, const float* __restrict__ arma_w,
    const float* __restrict__ arma_bias,
    const int* __restrict__ aa_off, const int* __restrict__ aa_src,
    const float* __restrict__ aa_nrm, float* __restrict__ gfull)
{
    __shared__ float Abuf[MPAD][GP];   // 33.8 KB
    __shared__ float Bbuf[MPAD][GP];   // 33.8 KB
    __shared__ int   s_off[M_M + 1];
    __shared__ int   s_src[EA_E];
    __shared__ float s_nrm[EA_E];
    int b = blockIdx.x / K_ST, k = blockIdx.x % K_ST;
    int tid = threadIdx.x;
    int oi = tid & 15;          // cols [oi*8, oi*8+8)
    int mi = tid >> 4;          // rows [mi*2, mi*2+2)
    int ob = oi * 8;
    const float* rcb = RC + (size_t)b * NS * M_M * G_DIM;

    if (tid < M_M + 1) s_off[tid] = aa_off[tid];
    if (tid < EA_E) { s_src[tid] = aa_src[tid]; s_nrm[tid] = aa_nrm[tid]; }

    for (int i = tid; i < MPAD * G_DIM; i += 512) {
        int m = i >> 7, o = i & 127;
        Abuf[m][o] = (m < M_M) ? rcb[(size_t)k * M_M * G_DIM + i] : 0.f;
        Bbuf[m][o] = 0.f;
    }
    __syncthreads();

    for (int t = 0; t < T_L; ++t) {
        if (t > 0) {
            const float* aw = arma_w + ((size_t)(t-1) * K_ST + k) * G_DIM * G_DIM;
            float4 acc[2][2];
            #pragma unroll
            for (int r = 0; r < 2; ++r) {
                acc[r][0] = make_float4(0.f,0.f,0.f,0.f);
                acc[r][1] = make_float4(0.f,0.f,0.f,0.f);
            }
            for (int p = 0; p < G_DIM; p += 4) {
                float4 wv[4][2];
                #pragma unroll
                for (int q = 0; q < 4; ++q) {
                    const float* wr = aw + (size_t)(p + q) * G_DIM + ob;
                    wv[q][0] = *(const float4*)wr;
                    wv[q][1] = *(const float4*)(wr + 4);
                }
                #pragma unroll
                for (int r = 0; r < 2; ++r) {
                    float4 xv = *(const float4*)&Bbuf[mi * 2 + r][p];
                    #pragma unroll
                    for (int hh = 0; hh < 2; ++hh) {
                        f4fma(acc[r][hh], xv.x, wv[0][hh]);
                        f4fma(acc[r][hh], xv.y, wv[1][hh]);
                        f4fma(acc[r][hh], xv.z, wv[2][hh]);
                        f4fma(acc[r][hh], xv.w, wv[3][hh]);
                    }
                }
            }
            __syncthreads();   // all Bbuf reads done before Abuf overwrite?
                               // (Abuf/Bbuf disjoint; barrier orders Abuf write
                               //  vs its readers below)
            #pragma unroll
            for (int r = 0; r < 2; ++r) {
                float* apr = &Abuf[mi * 2 + r][ob];
                *(float4*)apr       = acc[r][0];
                *(float4*)(apr + 4) = acc[r][1];
            }
            __syncthreads();
        }
        const float* rct = rcb + (size_t)(K_ST + t * K_ST + k) * M_M * G_DIM;
        const float* bb  = arma_bias + ((size_t)t * K_ST + k) * G_DIM;
        float4 bias0 = *(const float4*)(bb + ob);
        float4 bias1 = *(const float4*)(bb + ob + 4);
        #pragma unroll
        for (int r = 0; r < 2; ++r) {
            int m = mi * 2 + r;
            if (m < M_M) {
                const float* rr = rct + (size_t)m * G_DIM + ob;
                float4 v0 = bias0, v1 = bias1;
                f4add(v0, *(const float4*)rr);
                f4add(v1, *(const float4*)(rr + 4));
                int j0 = s_off[m], j1 = s_off[m + 1];
                for (int j = j0; j < j1; ++j) {
                    float nv = s_nrm[j];
                    const float* ap = &Abuf[s_src[j]][ob];
                    float4 a0 = *(const float4*)ap;
                    float4 a1 = *(const float4*)(ap + 4);
                    f4fma(v0, nv, a0);
                    f4fma(v1, nv, a1);
                }
                f4relu(v0);
                f4relu(v1);
                float* bp = &Bbuf[m][ob];
                *(float4*)bp       = v0;
                *(float4*)(bp + 4) = v1;
            }
        }
        __syncthreads();
    }
    float* gb = gfull + ((size_t)(b * K_ST + k)) * M_M * G_DIM;
    for (int i = tid; i < M_M * G_DIM; i += 512) {
        int m = i >> 7, o = i & 127;
        gb[i] = Bbuf[m][o];
    }
}

// ---------------------------------------------------------------------------
// Mean over K, amino attention readout, MLP head. One block per graph.
// ---------------------------------------------------------------------------
__global__ __launch_bounds__(128) void aa_readout_mlp(
    const float* __restrict__ gfull, const float* __restrict__ wa,
    const float* __restrict__ ba,
    const float* __restrict__ W1, const float* __restrict__ b1,
    const float* __restrict__ W2, const float* __restrict__ b2,
    const float* __restrict__ W3, const float* __restrict__ b3,
    const float* __restrict__ W4, const float* __restrict__ b4,
    float* __restrict__ out)
{
    __shared__ float g[M_M][G_DIM + 1];
    __shared__ float s2[M_M];
    __shared__ float p[G_DIM];
    __shared__ float r1[64], r2[32], r3[16];
    int b = blockIdx.x, tid = threadIdx.x;
    const float* g0 = gfull + (size_t)b * K_ST * M_M * G_DIM;
    for (int i = tid; i < M_M * G_DIM; i += 128) {
        int m = i >> 7, o = i & 127;
        g[m][o] = (g0[i] + g0[M_M*G_DIM + i] + g0[2*M_M*G_DIM + i]) * (1.f/3.f);
    }
    __syncthreads();
    if (tid < M_M) {
        float sv = ba[0];
        for (int o = 0; o < G_DIM; ++o) sv += g[tid][o] * wa[o];
        s2[tid] = sv;
    }
    __syncthreads();
    if (tid == 0) {
        float mx = -1e30f;
        for (int m = 0; m < M_M; ++m) mx = fmaxf(mx, s2[m]);
        float den = 0.f;
        for (int m = 0; m < M_M; ++m) den += expf(s2[m] - mx);
        float inv = 1.f / den;
        for (int m = 0; m < M_M; ++m) s2[m] = expf(s2[m] - mx) * inv;
    }
    __syncthreads();
    {
        float pv = 0.f;
        for (int m = 0; m < M_M; ++m) pv += g[m][tid] * s2[m];
        p[tid] = pv;
    }
    __syncthreads();
    if (tid < 64) {
        float v = b1[tid];
        for (int i = 0; i < 128; ++i) v += p[i] * W1[i * 64 + tid];
        r1[tid] = fmaxf(v, 0.f);
    }
    __syncthreads();
    if (tid < 32) {
        float v = b2[tid];
        for (int i = 0; i < 64; ++i) v += r1[i] * W2[i * 32 + tid];
        r2[tid] = fmaxf(v, 0.f);
    }
    __syncthreads();
    if (tid < 16) {
        float v = b3[tid];
        for (int i = 0; i < 32; ++i) v += r2[i] * W3[i * 16 + tid];
        r3[tid] = fmaxf(v, 0.f);
    }
    __syncthreads();
    if (tid == 0) {
        float v = b4[0];
        for (int i = 0; i < 16; ++i) v += r3[i] * W4[i];
        out[b] = v;
    }
}

// ---------------------------------------------------------------------------
extern "C" void kernel_launch(void* const* d_in, const int* in_sizes, int n_in,
                              void* d_out, int out_size, void* d_ws, size_t ws_size,
                              hipStream_t stream)
{
    (void)in_sizes; (void)n_in; (void)out_size; (void)ws_size;
    const float* x            = (const float*)d_in[0];
    const float* edge_attr    = (const float*)d_in[1];
    const float* aa_features  = (const float*)d_in[2];
    const int*   edge_index   = (const int*)  d_in[3];
    const int*   mono_labels  = (const int*)  d_in[4];
    const int*   amino_ei     = (const int*)  d_in[5];
    const float* W_e1 = (const float*)d_in[6];
    const float* b_e1 = (const float*)d_in[7];
    const float* root1= (const float*)d_in[8];
    const float* bias1= (const float*)d_in[9];
    const float* W_e2 = (const float*)d_in[10];
    const float* b_e2 = (const float*)d_in[11];
    const float* root2= (const float*)d_in[12];
    const float* bias2= (const float*)d_in[13];
    const float* Wa_atom = (const float*)d_in[14];
    const float* ba_atom = (const float*)d_in[15];
    const float* arma_init_w = (const float*)d_in[16];
    const float* arma_w      = (const float*)d_in[17];
    const float* arma_root_w = (const float*)d_in[18];
    const float* arma_bias   = (const float*)d_in[19];
    const float* Wa_aa = (const float*)d_in[20];
    const float* ba_aa = (const float*)d_in[21];
    const float* W1 = (const float*)d_in[22];
    const float* b1 = (const float*)d_in[23];
    const float* W2 = (const float*)d_in[24];
    const float* b2 = (const float*)d_in[25];
    const float* W3 = (const float*)d_in[26];
    const float* b3 = (const float*)d_in[27];
    const float* W4 = (const float*)d_in[28];
    const float* b4 = (const float*)d_in[29];

    float* ws = (float*)d_ws;
    float* h1    = ws;                                   // N*32
    float* h2    = h1   + (size_t)N_ATOMS * H1C;         // N*64
    float* h_aa  = h2   + (size_t)N_ATOMS * H2C;         // B*M*159
    float* sc    = h_aa + (size_t)B_G * M_M * XDIM;      // B*NPG (scores)
    int*   aa_off = (int*)(sc + (size_t)B_G * NPG);      // M+1
    int*   aa_src = aa_off + (M_M + 1);                  // EA
    float* aa_nrm = (float*)(aa_src + EA_E);             // EA
    int*   deg_off = (int*)(aa_nrm + EA_E);              // N+1
    int*   cursor  = deg_off + (N_ATOMS + 1);            // N (adjacent -> one memset)
    int*   order   = cursor + N_ATOMS;                   // E
    float* RC    = (float*)(order + E_EDGES);            // B*21*M*128 (26.9 MB)
    float* gfull = RC + (size_t)B_G * NS * M_M * G_DIM;  // B*3*M*128
    float* msg   = RC;   // alias: msg dead before rc_gemm writes RC

    (void)hipMemsetAsync(deg_off, 0, (2 * N_ATOMS + 1) * sizeof(int), stream);

    int eblocks = (E_EDGES + 255) / 256;
    int mblocks = (E_EDGES + 63) / 64;    // MFMA edge kernels: 64 edges/block

    // CSR build (shared by both convs)
    deg_count<<<eblocks, 256, 0, stream>>>(edge_index, deg_off);
    scan_kernel<<<1, 1024, 0, stream>>>(deg_off);
    fill_order<<<eblocks, 256, 0, stream>>>(edge_index, deg_off, cursor, order);

    // conv1 (MFMA, bf16 inputs / fp32 accumulate)
    edge_msg_mfma<DIN, H1C><<<mblocks, 256, 0, stream>>>(
        x, edge_attr, edge_index, W_e1, b_e1, msg);
    gather_update<DIN, H1C><<<(N_ATOMS + 7) / 8, 256, 0, stream>>>(
        msg, deg_off, order, x, root1, bias1, h1);
    // conv2 (MFMA)
    edge_msg_mfma<H1C, H2C><<<mblocks, 256, 0, stream>>>(
        h1, edge_attr, edge_index, W_e2, b_e2, msg);
    gather_update<H1C, H2C><<<(N_ATOMS + 3) / 4, 256, 0, stream>>>(
        msg, deg_off, order, h1, root2, bias2, h2);

    // atom attention readout (softmax fused into aggregate)
    atom_score<<<(N_ATOMS + 127) / 128, 256, 0, stream>>>(h2, Wa_atom, ba_atom, sc);
    atom_aggregate<<<3 * B_G, 256, 0, stream>>>(h2, sc, mono_labels, aa_features, h_aa);

    aa_norm_kernel<<<1, 128, 0, stream>>>(amino_ei, aa_off, aa_src, aa_nrm);
    rc_gemm<<<B_G * NS, 256, 0, stream>>>(h_aa, arma_init_w, arma_root_w, RC);
    arma_iter<<<B_G * K_ST, 512, 0, stream>>>(RC, arma_w, arma_bias,
                                              aa_off, aa_src, aa_nrm, gfull);
    aa_readout_mlp<<<B_G, 128, 0, stream>>>(gfull, Wa_aa, ba_aa, W1, b1, W2, b2, W3, b3, W4, b4,
                                            (float*)d_out);
}

// Round 18
// 544.218 us; speedup vs baseline: 1.0451x; 1.0451x over previous
//
#include <hip/hip_runtime.h>
#include <math.h>

#define N_ATOMS 50000
#define E_EDGES 100000
#define B_G     50
#define M_M     50
#define NPG     1000
#define DIN     32
#define H1C     32
#define H2C     64
#define DEC     16
#define AAF     95
#define G_DIM   128
#define K_ST    3
#define T_L     6
#define EA_E    98
#define XDIM    159          // H2 + AAF
#define NS      21           // K + T*K weight slices
#define MPAD    64           // M padded for regular tiling
#define GP      132          // G_DIM padded
#define XP      164          // XDIM padded for rc_gemm rows

typedef __attribute__((ext_vector_type(8))) short bf16x8;
typedef __attribute__((ext_vector_type(4))) float f32x4;

__device__ __forceinline__ short f2bf(float f) {
    unsigned int u = __float_as_uint(f);
    unsigned int r = (u + 0x7FFFu + ((u >> 16) & 1u)) >> 16;   // RNE
    return (short)r;
}
__device__ __forceinline__ float bf2f(short b) {
    return __uint_as_float(((unsigned int)(unsigned short)b) << 16);
}

__device__ __forceinline__ void f4fma(float4& d, float s, const float4& v) {
    d.x += s * v.x; d.y += s * v.y; d.z += s * v.z; d.w += s * v.w;
}
__device__ __forceinline__ void f4add(float4& d, const float4& v) {
    d.x += v.x; d.y += v.y; d.z += v.z; d.w += v.w;
}
__device__ __forceinline__ void f4relu(float4& d) {
    d.x = fmaxf(d.x, 0.f); d.y = fmaxf(d.y, 0.f);
    d.z = fmaxf(d.z, 0.f); d.w = fmaxf(d.w, 0.f);
}

// ---------------------------------------------------------------------------
// CSR build: degree count -> exclusive scan (1024-wide) -> bucket fill
// ---------------------------------------------------------------------------
__global__ __launch_bounds__(256) void deg_count(const int* __restrict__ eidx,
                                                 int* __restrict__ deg)
{
    int e = blockIdx.x * 256 + threadIdx.x;
    if (e >= E_EDGES) return;
    atomicAdd(&deg[eidx[E_EDGES + e]], 1);
}

__global__ __launch_bounds__(1024) void scan_kernel(int* __restrict__ deg_off)
{
    __shared__ int part[1024];
    int tid = threadIdx.x;
    const int SEG = (N_ATOMS + 1023) / 1024;   // 49
    int lo = tid * SEG;
    int hi = lo + SEG; if (hi > N_ATOMS) hi = N_ATOMS;
    int s = 0;
    for (int n = lo; n < hi; ++n) s += deg_off[n];
    part[tid] = s;
    __syncthreads();
    for (int off = 1; off < 1024; off <<= 1) {
        int v = part[tid];
        int add = (tid >= off) ? part[tid - off] : 0;
        __syncthreads();
        part[tid] = v + add;
        __syncthreads();
    }
    int run = (tid == 0) ? 0 : part[tid - 1];
    for (int n = lo; n < hi; ++n) {
        int d = deg_off[n];
        deg_off[n] = run;
        run += d;
    }
    if (tid == 1023) deg_off[N_ATOMS] = run;
}

__global__ __launch_bounds__(256) void fill_order(const int* __restrict__ eidx,
                                                  const int* __restrict__ off,
                                                  int* __restrict__ cursor,
                                                  int* __restrict__ order)
{
    int e = blockIdx.x * 256 + threadIdx.x;
    if (e >= E_EDGES) return;
    int d = eidx[E_EDGES + e];
    int pos = atomicAdd(&cursor[d], 1);
    order[off[d] + pos] = e;
}

// ---------------------------------------------------------------------------
// MFMA edge message kernel (R16, verified absmax 9.5e-7).
// ---------------------------------------------------------------------------
template<int FIN, int FOUT>
__global__ __launch_bounds__(256, 2) void edge_msg_mfma(
    const float* __restrict__ h, const float* __restrict__ ea,
    const int* __restrict__ eidx, const float* __restrict__ We,
    const float* __restrict__ be, float* __restrict__ msg)
{
    static_assert(FIN == 32, "K mapping assumes FIN==32");
    constexpr int K0  = DEC * FIN;        // 512
    constexpr int KS  = (K0 + FIN) / 32;  // 17
    constexpr int WTP = 552;
    constexpr int NT  = FOUT / 16;
    __shared__ short Wt[FOUT][WTP];
    __shared__ short hA[64][40];
    __shared__ short eaA[64][16];
    int tid = threadIdx.x;
    int ebase = blockIdx.x * 64;

    for (int i = tid; i < DEC * FIN * FOUT; i += 256) {
        int o  = i % FOUT;
        int fk = i / FOUT;
        Wt[o][fk] = f2bf(We[i]);
    }
    for (int i = tid; i < FIN * FOUT; i += 256) {
        int o = i % FOUT, ff = i / FOUT;
        Wt[o][K0 + ff] = f2bf(be[i]);
    }
    for (int i = tid; i < 64 * FIN; i += 256) {
        int r = i / FIN, f = i % FIN;
        int e = ebase + r; int es = (e < E_EDGES) ? e : 0;
        int s = eidx[es];
        hA[r][f] = f2bf(h[(size_t)s * FIN + f]);
    }
    for (int i = tid; i < 64 * DEC; i += 256) {
        int r = i / DEC, d = i % DEC;
        int e = ebase + r; int es = (e < E_EDGES) ? e : 0;
        eaA[r][d] = f2bf(ea[(size_t)es * DEC + d]);
    }
    __syncthreads();

    int lane = tid & 63;
    int wave = tid >> 6;
    int l16  = lane & 15;
    int quad = lane >> 4;

    float hf[8];
    {
        const short* hp = &hA[wave * 16 + l16][quad * 8];
        #pragma unroll
        for (int j = 0; j < 8; ++j) hf[j] = bf2f(hp[j]);
    }
    float eaf[16];
    {
        const short* ep = &eaA[wave * 16 + l16][0];
        #pragma unroll
        for (int d = 0; d < 16; ++d) eaf[d] = bf2f(ep[d]);
    }

    f32x4 acc[NT];
    #pragma unroll
    for (int nt = 0; nt < NT; ++nt) acc[nt] = (f32x4){0.f, 0.f, 0.f, 0.f};

    #pragma unroll
    for (int ks = 0; ks < KS; ++ks) {
        float fac = (ks < DEC) ? eaf[ks] : 1.0f;
        bf16x8 a;
        #pragma unroll
        for (int j = 0; j < 8; ++j) a[j] = f2bf(fac * hf[j]);
        #pragma unroll
        for (int nt = 0; nt < NT; ++nt) {
            const bf16x8 b = *(const bf16x8*)&Wt[nt * 16 + l16][ks * 32 + quad * 8];
            acc[nt] = __builtin_amdgcn_mfma_f32_16x16x32_bf16(a, b, acc[nt], 0, 0, 0);
        }
    }
    #pragma unroll
    for (int nt = 0; nt < NT; ++nt) {
        #pragma unroll
        for (int r = 0; r < 4; ++r) {
            int e = ebase + wave * 16 + quad * 4 + r;
            if (e < E_EDGES)
                msg[(size_t)e * FOUT + nt * 16 + l16] = acc[nt][r];
        }
    }
}

// ---------------------------------------------------------------------------
// Gather + node update fused
// ---------------------------------------------------------------------------
template<int FIN, int FOUT>
__global__ __launch_bounds__(256) void gather_update(
    const float* __restrict__ msg, const int* __restrict__ off,
    const int* __restrict__ order, const float* __restrict__ hin,
    const float* __restrict__ root, const float* __restrict__ bias,
    float* __restrict__ hout)
{
    constexpr int NPB = 256 / FOUT;
    __shared__ float rlds[FIN][FOUT];
    __shared__ float hlds[NPB][FIN];
    int tid = threadIdx.x;
    for (int i = tid; i < FIN * FOUT / 4; i += 256) {
        *(float4*)&rlds[0][i * 4] = *(const float4*)(root + i * 4);
    }
    int nb = blockIdx.x * NPB;
    for (int i = tid; i < NPB * FIN; i += 256) {
        int ln = i / FIN, f = i % FIN;
        int n = nb + ln;
        hlds[ln][f] = (n < N_ATOMS) ? hin[(size_t)n * FIN + f] : 0.f;
    }
    __syncthreads();

    int ln = tid / FOUT, o = tid % FOUT;
    int n = nb + ln;
    if (n >= N_ATOMS) return;
    float acc = bias[o];
    #pragma unroll 8
    for (int f = 0; f < FIN; ++f) acc += hlds[ln][f] * rlds[f][o];
    int j0 = off[n], j1 = off[n + 1];
    for (int j = j0; j < j1; ++j) {
        int e = order[j];
        acc += msg[(size_t)e * FOUT + o];
    }
    hout[(size_t)n * FOUT + o] = fmaxf(acc, 0.f);
}

// ---------------------------------------------------------------------------
// Atom attention: atom_score then atom_aggregate (softmax fused in-block)
// ---------------------------------------------------------------------------
__global__ __launch_bounds__(256) void atom_score(
    const float* __restrict__ h2, const float* __restrict__ wa,
    const float* __restrict__ ba, float* __restrict__ sc)
{
    __shared__ float hl[128][65];
    int nb = blockIdx.x * 128;
    int tid = threadIdx.x;
    for (int i = tid; i < 128 * 16; i += 256) {
        int r = i >> 4, c4 = i & 15;
        int n = nb + r;
        float4 v = (n < N_ATOMS) ? *(const float4*)(h2 + (size_t)n * H2C + c4 * 4)
                                 : make_float4(0.f, 0.f, 0.f, 0.f);
        *(float4*)&hl[r][c4 * 4] = v;
    }
    __syncthreads();
    if (tid < 128) {
        int n = nb + tid;
        if (n < N_ATOMS) {
            float sv = ba[0];
            #pragma unroll 8
            for (int o = 0; o < H2C; ++o) sv += hl[tid][o] * wa[o];
            sc[n] = sv;
        }
    }
}

__global__ __launch_bounds__(256) void atom_aggregate(
    const float* __restrict__ h2, const float* __restrict__ sc,
    const int* __restrict__ labels, const float* __restrict__ aaf,
    float* __restrict__ h_aa)
{
    int bx = blockIdx.x, tid = threadIdx.x;
    if (bx < 2 * B_G) {
        __shared__ float aa8[8][M_M][32];   // 51.2 KB
        __shared__ float red[256];
        int b = bx >> 1, half = bx & 1;
        int g = tid >> 5, o = tid & 31;
        const float* sb = sc + (size_t)b * NPG;
        float lmax = -1e30f;
        for (int n = tid; n < NPG; n += 256) lmax = fmaxf(lmax, sb[n]);
        red[tid] = lmax;
        __syncthreads();
        for (int off = 128; off > 0; off >>= 1) {
            if (tid < off) red[tid] = fmaxf(red[tid], red[tid + off]);
            __syncthreads();
        }
        float mx = red[0];
        __syncthreads();
        float lsum = 0.f;
        for (int n = tid; n < NPG; n += 256) lsum += expf(sb[n] - mx);
        red[tid] = lsum;
        __syncthreads();
        for (int off = 128; off > 0; off >>= 1) {
            if (tid < off) red[tid] += red[tid + off];
            __syncthreads();
        }
        float inv = 1.f / red[0];
        __syncthreads();
        for (int i = tid; i < 8 * M_M * 32; i += 256) ((float*)aa8)[i] = 0.f;
        __syncthreads();
        const float* hb = h2 + (size_t)b * NPG * H2C + half * 32;
        for (int n = g; n < NPG; n += 8) {
            int lbl = labels[b * NPG + n];
            float w = expf(sb[n] - mx) * inv;
            float hvv = hb[(size_t)n * H2C + o];
            aa8[g][lbl][o] += hvv * w;
        }
        __syncthreads();
        float* ob = h_aa + (size_t)b * M_M * XDIM + half * 32;
        for (int i = tid; i < M_M * 32; i += 256) {
            int m = i >> 5, oo = i & 31;
            float v = 0.f;
            #pragma unroll
            for (int gg = 0; gg < 8; ++gg) v += aa8[gg][m][oo];
            ob[m * XDIM + oo] = v;
        }
    } else {
        int b = bx - 2 * B_G;
        const float* ab = aaf + (size_t)b * M_M * AAF;
        float* ob = h_aa + (size_t)b * M_M * XDIM + H2C;
        for (int i = tid; i < M_M * AAF; i += 256) {
            int m = i / AAF, j = i - m * AAF;
            ob[m * XDIM + j] = ab[i];
        }
    }
}

// ---------------------------------------------------------------------------
// Amino-graph gcn_norm + dst-sorted CSR build (tiny, 1 block)
// ---------------------------------------------------------------------------
__global__ void aa_norm_kernel(const int* __restrict__ aei,
                               int* __restrict__ aa_off,
                               int* __restrict__ aa_src,
                               float* __restrict__ aa_nrm)
{
    __shared__ int   sdeg[M_M];
    __shared__ int   scur[M_M];
    __shared__ float sdinv[M_M];
    __shared__ int   soff[M_M + 1];
    int tid = threadIdx.x;
    if (tid < M_M) { sdeg[tid] = 0; scur[tid] = 0; }
    __syncthreads();
    if (tid < EA_E) atomicAdd(&sdeg[aei[EA_E + tid]], 1);
    __syncthreads();
    if (tid < M_M) {
        float dv = (float)sdeg[tid];
        sdinv[tid] = (dv > 0.f) ? (1.f / sqrtf(fmaxf(dv, 1.f))) : 0.f;
    }
    __syncthreads();
    if (tid == 0) {
        soff[0] = 0;
        for (int m = 0; m < M_M; ++m) soff[m + 1] = soff[m] + sdeg[m];
    }
    __syncthreads();
    if (tid < EA_E) {
        int ss = aei[tid], dd = aei[EA_E + tid];
        int pos = atomicAdd(&scur[dd], 1);
        int idx = soff[dd] + pos;
        aa_src[idx] = ss;
        aa_nrm[idx] = sdinv[ss] * sdinv[dd];
    }
    if (tid < M_M + 1) aa_off[tid] = soff[tid];
}

// ---------------------------------------------------------------------------
// Batched root GEMM, arma-style 4x8 tile. x0 in padded-row LDS (XP=164).
// ---------------------------------------------------------------------------
__global__ __launch_bounds__(256) void rc_gemm(
    const float* __restrict__ h_aa, const float* __restrict__ init_w,
    const float* __restrict__ root_w, float* __restrict__ RC)
{
    __shared__ float x0[MPAD][XP];   // 42 KB
    int b = blockIdx.x / NS, s = blockIdx.x % NS;
    int tid = threadIdx.x;
    int oi = tid & 15, mi = tid >> 4;
    int ob = oi * 8;
    const float* xb = h_aa + (size_t)b * M_M * XDIM;
    for (int i = tid; i < MPAD * XP; i += 256) {
        int m = i / XP, f = i - m * XP;
        x0[m][f] = (m < M_M && f < XDIM) ? xb[m * XDIM + f] : 0.f;
    }
    __syncthreads();
    const float* W = (s < K_ST) ? (init_w + (size_t)s * XDIM * G_DIM)
                                : (root_w + (size_t)(s - K_ST) * XDIM * G_DIM);
    float4 acc[4][2];
    #pragma unroll
    for (int r = 0; r < 4; ++r) {
        acc[r][0] = make_float4(0.f,0.f,0.f,0.f);
        acc[r][1] = make_float4(0.f,0.f,0.f,0.f);
    }
    int p = 0;
    for (; p + 4 <= XDIM; p += 4) {
        float4 wv[4][2];
        #pragma unroll
        for (int q = 0; q < 4; ++q) {
            const float* wr = W + (size_t)(p + q) * G_DIM + ob;
            wv[q][0] = *(const float4*)wr;
            wv[q][1] = *(const float4*)(wr + 4);
        }
        #pragma unroll
        for (int r = 0; r < 4; ++r) {
            float4 xv = *(const float4*)&x0[mi * 4 + r][p];
            #pragma unroll
            for (int hh = 0; hh < 2; ++hh) {
                f4fma(acc[r][hh], xv.x, wv[0][hh]);
                f4fma(acc[r][hh], xv.y, wv[1][hh]);
                f4fma(acc[r][hh], xv.z, wv[2][hh]);
                f4fma(acc[r][hh], xv.w, wv[3][hh]);
            }
        }
    }
    for (; p < XDIM; ++p) {
        const float* wr = W + (size_t)p * G_DIM + ob;
        float4 w0 = *(const float4*)wr;
        float4 w1 = *(const float4*)(wr + 4);
        #pragma unroll
        for (int r = 0; r < 4; ++r) {
            float xv = x0[mi * 4 + r][p];
            f4fma(acc[r][0], xv, w0);
            f4fma(acc[r][1], xv, w1);
        }
    }
    float* op = RC + ((size_t)(b * NS + s)) * M_M * G_DIM;
    #pragma unroll
    for (int r = 0; r < 4; ++r) {
        int m = mi * 4 + r;
        if (m < M_M) {
            float* pp = op + (size_t)m * G_DIM + ob;
            *(float4*)pp       = acc[r][0];
            *(float4*)(pp + 4) = acc[r][1];
        }
    }
}

// ---------------------------------------------------------------------------
// ARMA recurrence: one block per (b,k). 512 threads, 2x8 per-thread tile.
// Each t-step's W matrix is bulk-copied into LDS first (one pipelined
// coalesced pass) instead of being dribbled through ~200-cyc L2 loads inside
// the matmul loop — R17 showed wave count doesn't hide those (VALUBusy 12%
// at both 1 and 2 waves/SIMD). LDS: 33.8+33.8+67.6 = 135 KB (1 block/CU).
// ---------------------------------------------------------------------------
__global__ __launch_bounds__(512) void arma_iter(
    const float* __restrict__ RC, const float* __restrict__ arma_w,
    const float* __restrict__ arma_bias,
    const int* __restrict__ aa_off, const int* __restrict__ aa_src,
    const float* __restrict__ aa_nrm, float* __restrict__ gfull)
{
    __shared__ float Abuf[MPAD][GP];   // 33.8 KB
    __shared__ float Bbuf[MPAD][GP];   // 33.8 KB
    __shared__ float Wlds[G_DIM][GP];  // 67.6 KB, current t's aw (padded rows)
    __shared__ int   s_off[M_M + 1];
    __shared__ int   s_src[EA_E];
    __shared__ float s_nrm[EA_E];
    int b = blockIdx.x / K_ST, k = blockIdx.x % K_ST;
    int tid = threadIdx.x;
    int oi = tid & 15;          // cols [oi*8, oi*8+8)
    int mi = tid >> 4;          // rows [mi*2, mi*2+2)
    int ob = oi * 8;
    const float* rcb = RC + (size_t)b * NS * M_M * G_DIM;

    if (tid < M_M + 1) s_off[tid] = aa_off[tid];
    if (tid < EA_E) { s_src[tid] = aa_src[tid]; s_nrm[tid] = aa_nrm[tid]; }

    for (int i = tid; i < MPAD * G_DIM; i += 512) {
        int m = i >> 7, o = i & 127;
        Abuf[m][o] = (m < M_M) ? rcb[(size_t)k * M_M * G_DIM + i] : 0.f;
        Bbuf[m][o] = 0.f;
    }
    __syncthreads();

    for (int t = 0; t < T_L; ++t) {
        if (t > 0) {
            // bulk-stage aw into LDS: 4096 float4, 8 per thread, all independent
            const float* aw = arma_w + ((size_t)(t-1) * K_ST + k) * G_DIM * G_DIM;
            #pragma unroll
            for (int i = 0; i < 8; ++i) {
                int idx = (tid + i * 512) * 4;          // flat float index
                int row = idx >> 7, col = idx & 127;
                *(float4*)&Wlds[row][col] = *(const float4*)(aw + idx);
            }
            __syncthreads();
            // matmul: Abuf = Bbuf @ Wlds  (all operands in LDS)
            float4 acc[2][2];
            #pragma unroll
            for (int r = 0; r < 2; ++r) {
                acc[r][0] = make_float4(0.f,0.f,0.f,0.f);
                acc[r][1] = make_float4(0.f,0.f,0.f,0.f);
            }
            for (int p = 0; p < G_DIM; p += 4) {
                float4 wv[4][2];
                #pragma unroll
                for (int q = 0; q < 4; ++q) {
                    wv[q][0] = *(const float4*)&Wlds[p + q][ob];
                    wv[q][1] = *(const float4*)&Wlds[p + q][ob + 4];
                }
                #pragma unroll
                for (int r = 0; r < 2; ++r) {
                    float4 xv = *(const float4*)&Bbuf[mi * 2 + r][p];
                    #pragma unroll
                    for (int hh = 0; hh < 2; ++hh) {
                        f4fma(acc[r][hh], xv.x, wv[0][hh]);
                        f4fma(acc[r][hh], xv.y, wv[1][hh]);
                        f4fma(acc[r][hh], xv.z, wv[2][hh]);
                        f4fma(acc[r][hh], xv.w, wv[3][hh]);
                    }
                }
            }
            __syncthreads();   // Bbuf/Wlds reads complete
            #pragma unroll
            for (int r = 0; r < 2; ++r) {
                float* apr = &Abuf[mi * 2 + r][ob];
                *(float4*)apr       = acc[r][0];
                *(float4*)(apr + 4) = acc[r][1];
            }
            __syncthreads();   // Abuf ready for prop
        }
        const float* rct = rcb + (size_t)(K_ST + t * K_ST + k) * M_M * G_DIM;
        const float* bb  = arma_bias + ((size_t)t * K_ST + k) * G_DIM;
        float4 bias0 = *(const float4*)(bb + ob);
        float4 bias1 = *(const float4*)(bb + ob + 4);
        #pragma unroll
        for (int r = 0; r < 2; ++r) {
            int m = mi * 2 + r;
            if (m < M_M) {
                const float* rr = rct + (size_t)m * G_DIM + ob;
                float4 v0 = bias0, v1 = bias1;
                f4add(v0, *(const float4*)rr);
                f4add(v1, *(const float4*)(rr + 4));
                int j0 = s_off[m], j1 = s_off[m + 1];
                for (int j = j0; j < j1; ++j) {
                    float nv = s_nrm[j];
                    const float* ap = &Abuf[s_src[j]][ob];
                    float4 a0 = *(const float4*)ap;
                    float4 a1 = *(const float4*)(ap + 4);
                    f4fma(v0, nv, a0);
                    f4fma(v1, nv, a1);
                }
                f4relu(v0);
                f4relu(v1);
                float* bp = &Bbuf[m][ob];
                *(float4*)bp       = v0;
                *(float4*)(bp + 4) = v1;
            }
        }
        __syncthreads();
    }
    float* gb = gfull + ((size_t)(b * K_ST + k)) * M_M * G_DIM;
    for (int i = tid; i < M_M * G_DIM; i += 512) {
        int m = i >> 7, o = i & 127;
        gb[i] = Bbuf[m][o];
    }
}

// ---------------------------------------------------------------------------
// Mean over K, amino attention readout, MLP head. One block per graph.
// ---------------------------------------------------------------------------
__global__ __launch_bounds__(128) void aa_readout_mlp(
    const float* __restrict__ gfull, const float* __restrict__ wa,
    const float* __restrict__ ba,
    const float* __restrict__ W1, const float* __restrict__ b1,
    const float* __restrict__ W2, const float* __restrict__ b2,
    const float* __restrict__ W3, const float* __restrict__ b3,
    const float* __restrict__ W4, const float* __restrict__ b4,
    float* __restrict__ out)
{
    __shared__ float g[M_M][G_DIM + 1];
    __shared__ float s2[M_M];
    __shared__ float p[G_DIM];
    __shared__ float r1[64], r2[32], r3[16];
    int b = blockIdx.x, tid = threadIdx.x;
    const float* g0 = gfull + (size_t)b * K_ST * M_M * G_DIM;
    for (int i = tid; i < M_M * G_DIM; i += 128) {
        int m = i >> 7, o = i & 127;
        g[m][o] = (g0[i] + g0[M_M*G_DIM + i] + g0[2*M_M*G_DIM + i]) * (1.f/3.f);
    }
    __syncthreads();
    if (tid < M_M) {
        float sv = ba[0];
        for (int o = 0; o < G_DIM; ++o) sv += g[tid][o] * wa[o];
        s2[tid] = sv;
    }
    __syncthreads();
    if (tid == 0) {
        float mx = -1e30f;
        for (int m = 0; m < M_M; ++m) mx = fmaxf(mx, s2[m]);
        float den = 0.f;
        for (int m = 0; m < M_M; ++m) den += expf(s2[m] - mx);
        float inv = 1.f / den;
        for (int m = 0; m < M_M; ++m) s2[m] = expf(s2[m] - mx) * inv;
    }
    __syncthreads();
    {
        float pv = 0.f;
        for (int m = 0; m < M_M; ++m) pv += g[m][tid] * s2[m];
        p[tid] = pv;
    }
    __syncthreads();
    if (tid < 64) {
        float v = b1[tid];
        for (int i = 0; i < 128; ++i) v += p[i] * W1[i * 64 + tid];
        r1[tid] = fmaxf(v, 0.f);
    }
    __syncthreads();
    if (tid < 32) {
        float v = b2[tid];
        for (int i = 0; i < 64; ++i) v += r1[i] * W2[i * 32 + tid];
        r2[tid] = fmaxf(v, 0.f);
    }
    __syncthreads();
    if (tid < 16) {
        float v = b3[tid];
        for (int i = 0; i < 32; ++i) v += r2[i] * W3[i * 16 + tid];
        r3[tid] = fmaxf(v, 0.f);
    }
    __syncthreads();
    if (tid == 0) {
        float v = b4[0];
        for (int i = 0; i < 16; ++i) v += r3[i] * W4[i];
        out[b] = v;
    }
}

// ---------------------------------------------------------------------------
extern "C" void kernel_launch(void* const* d_in, const int* in_sizes, int n_in,
                              void* d_out, int out_size, void* d_ws, size_t ws_size,
                              hipStream_t stream)
{
    (void)in_sizes; (void)n_in; (void)out_size; (void)ws_size;
    const float* x            = (const float*)d_in[0];
    const float* edge_attr    = (const float*)d_in[1];
    const float* aa_features  = (const float*)d_in[2];
    const int*   edge_index   = (const int*)  d_in[3];
    const int*   mono_labels  = (const int*)  d_in[4];
    const int*   amino_ei     = (const int*)  d_in[5];
    const float* W_e1 = (const float*)d_in[6];
    const float* b_e1 = (const float*)d_in[7];
    const float* root1= (const float*)d_in[8];
    const float* bias1= (const float*)d_in[9];
    const float* W_e2 = (const float*)d_in[10];
    const float* b_e2 = (const float*)d_in[11];
    const float* root2= (const float*)d_in[12];
    const float* bias2= (const float*)d_in[13];
    const float* Wa_atom = (const float*)d_in[14];
    const float* ba_atom = (const float*)d_in[15];
    const float* arma_init_w = (const float*)d_in[16];
    const float* arma_w      = (const float*)d_in[17];
    const float* arma_root_w = (const float*)d_in[18];
    const float* arma_bias   = (const float*)d_in[19];
    const float* Wa_aa = (const float*)d_in[20];
    const float* ba_aa = (const float*)d_in[21];
    const float* W1 = (const float*)d_in[22];
    const float* b1 = (const float*)d_in[23];
    const float* W2 = (const float*)d_in[24];
    const float* b2 = (const float*)d_in[25];
    const float* W3 = (const float*)d_in[26];
    const float* b3 = (const float*)d_in[27];
    const float* W4 = (const float*)d_in[28];
    const float* b4 = (const float*)d_in[29];

    float* ws = (float*)d_ws;
    float* h1    = ws;                                   // N*32
    float* h2    = h1   + (size_t)N_ATOMS * H1C;         // N*64
    float* h_aa  = h2   + (size_t)N_ATOMS * H2C;         // B*M*159
    float* sc    = h_aa + (size_t)B_G * M_M * XDIM;      // B*NPG (scores)
    int*   aa_off = (int*)(sc + (size_t)B_G * NPG);      // M+1
    int*   aa_src = aa_off + (M_M + 1);                  // EA
    float* aa_nrm = (float*)(aa_src + EA_E);             // EA
    int*   deg_off = (int*)(aa_nrm + EA_E);              // N+1
    int*   cursor  = deg_off + (N_ATOMS + 1);            // N (adjacent -> one memset)
    int*   order   = cursor + N_ATOMS;                   // E
    float* RC    = (float*)(order + E_EDGES);            // B*21*M*128 (26.9 MB)
    float* gfull = RC + (size_t)B_G * NS * M_M * G_DIM;  // B*3*M*128
    float* msg   = RC;   // alias: msg dead before rc_gemm writes RC

    (void)hipMemsetAsync(deg_off, 0, (2 * N_ATOMS + 1) * sizeof(int), stream);

    int eblocks = (E_EDGES + 255) / 256;
    int mblocks = (E_EDGES + 63) / 64;    // MFMA edge kernels: 64 edges/block

    // CSR build (shared by both convs)
    deg_count<<<eblocks, 256, 0, stream>>>(edge_index, deg_off);
    scan_kernel<<<1, 1024, 0, stream>>>(deg_off);
    fill_order<<<eblocks, 256, 0, stream>>>(edge_index, deg_off, cursor, order);

    // conv1 (MFMA, bf16 inputs / fp32 accumulate)
    edge_msg_mfma<DIN, H1C><<<mblocks, 256, 0, stream>>>(
        x, edge_attr, edge_index, W_e1, b_e1, msg);
    gather_update<DIN, H1C><<<(N_ATOMS + 7) / 8, 256, 0, stream>>>(
        msg, deg_off, order, x, root1, bias1, h1);
    // conv2 (MFMA)
    edge_msg_mfma<H1C, H2C><<<mblocks, 256, 0, stream>>>(
        h1, edge_attr, edge_index, W_e2, b_e2, msg);
    gather_update<H1C, H2C><<<(N_ATOMS + 3) / 4, 256, 0, stream>>>(
        msg, deg_off, order, h1, root2, bias2, h2);

    // atom attention readout (softmax fused into aggregate)
    atom_score<<<(N_ATOMS + 127) / 128, 256, 0, stream>>>(h2, Wa_atom, ba_atom, sc);
    atom_aggregate<<<3 * B_G, 256, 0, stream>>>(h2, sc, mono_labels, aa_features, h_aa);

    aa_norm_kernel<<<1, 128, 0, stream>>>(amino_ei, aa_off, aa_src, aa_nrm);
    rc_gemm<<<B_G * NS, 256, 0, stream>>>(h_aa, arma_init_w, arma_root_w, RC);
    arma_iter<<<B_G * K_ST, 512, 0, stream>>>(RC, arma_w, arma_bias,
                                              aa_off, aa_src, aa_nrm, gfull);
    aa_readout_mlp<<<B_G, 128, 0, stream>>>(gfull, Wa_aa, ba_aa, W1, b1, W2, b2, W3, b3, W4, b4,
                                            (float*)d_out);
}

// Round 19
// 479.500 us; speedup vs baseline: 1.1861x; 1.1350x over previous
//
#include <hip/hip_runtime.h>
#include <math.h>

#define N_ATOMS 50000
#define E_EDGES 100000
#define B_G     50
#define M_M     50
#define NPG     1000
#define DIN     32
#define H1C     32
#define H2C     64
#define DEC     16
#define AAF     95
#define G_DIM   128
#define K_ST    3
#define T_L     6
#define EA_E    98
#define XDIM    159          // H2 + AAF
#define NS      21           // K + T*K weight slices
#define MPAD    64           // M padded for regular tiling
#define GP      132          // G_DIM padded
#define XP      164          // XDIM padded for rc_gemm rows
#define NSB     ((N_ATOMS + 255) / 256)   // 196 scan blocks

typedef __attribute__((ext_vector_type(8))) short bf16x8;
typedef __attribute__((ext_vector_type(4))) float f32x4;

__device__ __forceinline__ short f2bf(float f) {
    unsigned int u = __float_as_uint(f);
    unsigned int r = (u + 0x7FFFu + ((u >> 16) & 1u)) >> 16;   // RNE
    return (short)r;
}
__device__ __forceinline__ float bf2f(short b) {
    return __uint_as_float(((unsigned int)(unsigned short)b) << 16);
}

__device__ __forceinline__ void f4fma(float4& d, float s, const float4& v) {
    d.x += s * v.x; d.y += s * v.y; d.z += s * v.z; d.w += s * v.w;
}
__device__ __forceinline__ void f4add(float4& d, const float4& v) {
    d.x += v.x; d.y += v.y; d.z += v.z; d.w += v.w;
}
__device__ __forceinline__ void f4relu(float4& d) {
    d.x = fmaxf(d.x, 0.f); d.y = fmaxf(d.y, 0.f);
    d.z = fmaxf(d.z, 0.f); d.w = fmaxf(d.w, 0.f);
}

// ---------------------------------------------------------------------------
// CSR build: degree count -> 3-phase parallel scan -> bucket fill
// (old single-block scan was 77us — one CU, serial dependent passes)
// ---------------------------------------------------------------------------
__global__ __launch_bounds__(256) void deg_count(const int* __restrict__ eidx,
                                                 int* __restrict__ deg)
{
    int e = blockIdx.x * 256 + threadIdx.x;
    if (e >= E_EDGES) return;
    atomicAdd(&deg[eidx[E_EDGES + e]], 1);
}

__global__ __launch_bounds__(256) void scan_part(const int* __restrict__ deg,
                                                 int* __restrict__ bsum)
{
    __shared__ int tmp[256];
    int tid = threadIdx.x;
    int n = blockIdx.x * 256 + tid;
    tmp[tid] = (n < N_ATOMS) ? deg[n] : 0;
    __syncthreads();
    for (int off = 128; off > 0; off >>= 1) {
        if (tid < off) tmp[tid] += tmp[tid + off];
        __syncthreads();
    }
    if (tid == 0) bsum[blockIdx.x] = tmp[0];
}

__global__ __launch_bounds__(256) void scan_mid(const int* __restrict__ bsum,
                                                int* __restrict__ bpre)
{
    __shared__ int tmp[256];
    int tid = threadIdx.x;
    int v = (tid < NSB) ? bsum[tid] : 0;
    tmp[tid] = v;
    __syncthreads();
    for (int off = 1; off < 256; off <<= 1) {
        int t = tmp[tid];
        int add = (tid >= off) ? tmp[tid - off] : 0;
        __syncthreads();
        tmp[tid] = t + add;
        __syncthreads();
    }
    if (tid < NSB) bpre[tid] = tmp[tid] - v;   // exclusive
}

__global__ __launch_bounds__(256) void scan_out(int* __restrict__ deg_off,
                                                const int* __restrict__ bpre)
{
    __shared__ int tmp[256];
    int tid = threadIdx.x;
    int n = blockIdx.x * 256 + tid;
    int v = (n < N_ATOMS) ? deg_off[n] : 0;
    tmp[tid] = v;
    __syncthreads();
    for (int off = 1; off < 256; off <<= 1) {
        int t = tmp[tid];
        int add = (tid >= off) ? tmp[tid - off] : 0;
        __syncthreads();
        tmp[tid] = t + add;
        __syncthreads();
    }
    int incl = tmp[tid];
    int base = bpre[blockIdx.x];
    if (n < N_ATOMS) deg_off[n] = base + incl - v;
    if (n == N_ATOMS - 1) deg_off[N_ATOMS] = base + incl;
}

__global__ __launch_bounds__(256) void fill_order(const int* __restrict__ eidx,
                                                  const int* __restrict__ off,
                                                  int* __restrict__ cursor,
                                                  int* __restrict__ order)
{
    int e = blockIdx.x * 256 + threadIdx.x;
    if (e >= E_EDGES) return;
    int d = eidx[E_EDGES + e];
    int pos = atomicAdd(&cursor[d], 1);
    order[off[d] + pos] = e;
}

// ---------------------------------------------------------------------------
// MFMA edge message kernel (R16, verified absmax 9.5e-7).
// ---------------------------------------------------------------------------
template<int FIN, int FOUT>
__global__ __launch_bounds__(256, 2) void edge_msg_mfma(
    const float* __restrict__ h, const float* __restrict__ ea,
    const int* __restrict__ eidx, const float* __restrict__ We,
    const float* __restrict__ be, float* __restrict__ msg)
{
    static_assert(FIN == 32, "K mapping assumes FIN==32");
    constexpr int K0  = DEC * FIN;        // 512
    constexpr int KS  = (K0 + FIN) / 32;  // 17
    constexpr int WTP = 552;
    constexpr int NT  = FOUT / 16;
    __shared__ short Wt[FOUT][WTP];
    __shared__ short hA[64][40];
    __shared__ short eaA[64][16];
    int tid = threadIdx.x;
    int ebase = blockIdx.x * 64;

    for (int i = tid; i < DEC * FIN * FOUT; i += 256) {
        int o  = i % FOUT;
        int fk = i / FOUT;
        Wt[o][fk] = f2bf(We[i]);
    }
    for (int i = tid; i < FIN * FOUT; i += 256) {
        int o = i % FOUT, ff = i / FOUT;
        Wt[o][K0 + ff] = f2bf(be[i]);
    }
    for (int i = tid; i < 64 * FIN; i += 256) {
        int r = i / FIN, f = i % FIN;
        int e = ebase + r; int es = (e < E_EDGES) ? e : 0;
        int s = eidx[es];
        hA[r][f] = f2bf(h[(size_t)s * FIN + f]);
    }
    for (int i = tid; i < 64 * DEC; i += 256) {
        int r = i / DEC, d = i % DEC;
        int e = ebase + r; int es = (e < E_EDGES) ? e : 0;
        eaA[r][d] = f2bf(ea[(size_t)es * DEC + d]);
    }
    __syncthreads();

    int lane = tid & 63;
    int wave = tid >> 6;
    int l16  = lane & 15;
    int quad = lane >> 4;

    float hf[8];
    {
        const short* hp = &hA[wave * 16 + l16][quad * 8];
        #pragma unroll
        for (int j = 0; j < 8; ++j) hf[j] = bf2f(hp[j]);
    }
    float eaf[16];
    {
        const short* ep = &eaA[wave * 16 + l16][0];
        #pragma unroll
        for (int d = 0; d < 16; ++d) eaf[d] = bf2f(ep[d]);
    }

    f32x4 acc[NT];
    #pragma unroll
    for (int nt = 0; nt < NT; ++nt) acc[nt] = (f32x4){0.f, 0.f, 0.f, 0.f};

    #pragma unroll
    for (int ks = 0; ks < KS; ++ks) {
        float fac = (ks < DEC) ? eaf[ks] : 1.0f;
        bf16x8 a;
        #pragma unroll
        for (int j = 0; j < 8; ++j) a[j] = f2bf(fac * hf[j]);
        #pragma unroll
        for (int nt = 0; nt < NT; ++nt) {
            const bf16x8 b = *(const bf16x8*)&Wt[nt * 16 + l16][ks * 32 + quad * 8];
            acc[nt] = __builtin_amdgcn_mfma_f32_16x16x32_bf16(a, b, acc[nt], 0, 0, 0);
        }
    }
    #pragma unroll
    for (int nt = 0; nt < NT; ++nt) {
        #pragma unroll
        for (int r = 0; r < 4; ++r) {
            int e = ebase + wave * 16 + quad * 4 + r;
            if (e < E_EDGES)
                msg[(size_t)e * FOUT + nt * 16 + l16] = acc[nt][r];
        }
    }
}

// ---------------------------------------------------------------------------
// Gather + node update fused
// ---------------------------------------------------------------------------
template<int FIN, int FOUT>
__global__ __launch_bounds__(256) void gather_update(
    const float* __restrict__ msg, const int* __restrict__ off,
    const int* __restrict__ order, const float* __restrict__ hin,
    const float* __restrict__ root, const float* __restrict__ bias,
    float* __restrict__ hout)
{
    constexpr int NPB = 256 / FOUT;
    __shared__ float rlds[FIN][FOUT];
    __shared__ float hlds[NPB][FIN];
    int tid = threadIdx.x;
    for (int i = tid; i < FIN * FOUT / 4; i += 256) {
        *(float4*)&rlds[0][i * 4] = *(const float4*)(root + i * 4);
    }
    int nb = blockIdx.x * NPB;
    for (int i = tid; i < NPB * FIN; i += 256) {
        int ln = i / FIN, f = i % FIN;
        int n = nb + ln;
        hlds[ln][f] = (n < N_ATOMS) ? hin[(size_t)n * FIN + f] : 0.f;
    }
    __syncthreads();

    int ln = tid / FOUT, o = tid % FOUT;
    int n = nb + ln;
    if (n >= N_ATOMS) return;
    float acc = bias[o];
    #pragma unroll 8
    for (int f = 0; f < FIN; ++f) acc += hlds[ln][f] * rlds[f][o];
    int j0 = off[n], j1 = off[n + 1];
    for (int j = j0; j < j1; ++j) {
        int e = order[j];
        acc += msg[(size_t)e * FOUT + o];
    }
    hout[(size_t)n * FOUT + o] = fmaxf(acc, 0.f);
}

// ---------------------------------------------------------------------------
// Atom attention: atom_score then atom_aggregate (softmax fused in-block)
// ---------------------------------------------------------------------------
__global__ __launch_bounds__(256) void atom_score(
    const float* __restrict__ h2, const float* __restrict__ wa,
    const float* __restrict__ ba, float* __restrict__ sc)
{
    __shared__ float hl[128][65];
    int nb = blockIdx.x * 128;
    int tid = threadIdx.x;
    for (int i = tid; i < 128 * 16; i += 256) {
        int r = i >> 4, c4 = i & 15;
        int n = nb + r;
        float4 v = (n < N_ATOMS) ? *(const float4*)(h2 + (size_t)n * H2C + c4 * 4)
                                 : make_float4(0.f, 0.f, 0.f, 0.f);
        *(float4*)&hl[r][c4 * 4] = v;
    }
    __syncthreads();
    if (tid < 128) {
        int n = nb + tid;
        if (n < N_ATOMS) {
            float sv = ba[0];
            #pragma unroll 8
            for (int o = 0; o < H2C; ++o) sv += hl[tid][o] * wa[o];
            sc[n] = sv;
        }
    }
}

__global__ __launch_bounds__(256) void atom_aggregate(
    const float* __restrict__ h2, const float* __restrict__ sc,
    const int* __restrict__ labels, const float* __restrict__ aaf,
    float* __restrict__ h_aa)
{
    int bx = blockIdx.x, tid = threadIdx.x;
    if (bx < 2 * B_G) {
        __shared__ float aa8[8][M_M][32];   // 51.2 KB
        __shared__ float red[256];
        int b = bx >> 1, half = bx & 1;
        int g = tid >> 5, o = tid & 31;
        const float* sb = sc + (size_t)b * NPG;
        float lmax = -1e30f;
        for (int n = tid; n < NPG; n += 256) lmax = fmaxf(lmax, sb[n]);
        red[tid] = lmax;
        __syncthreads();
        for (int off = 128; off > 0; off >>= 1) {
            if (tid < off) red[tid] = fmaxf(red[tid], red[tid + off]);
            __syncthreads();
        }
        float mx = red[0];
        __syncthreads();
        float lsum = 0.f;
        for (int n = tid; n < NPG; n += 256) lsum += expf(sb[n] - mx);
        red[tid] = lsum;
        __syncthreads();
        for (int off = 128; off > 0; off >>= 1) {
            if (tid < off) red[tid] += red[tid + off];
            __syncthreads();
        }
        float inv = 1.f / red[0];
        __syncthreads();
        for (int i = tid; i < 8 * M_M * 32; i += 256) ((float*)aa8)[i] = 0.f;
        __syncthreads();
        const float* hb = h2 + (size_t)b * NPG * H2C + half * 32;
        for (int n = g; n < NPG; n += 8) {
            int lbl = labels[b * NPG + n];
            float w = expf(sb[n] - mx) * inv;
            float hvv = hb[(size_t)n * H2C + o];
            aa8[g][lbl][o] += hvv * w;
        }
        __syncthreads();
        float* ob = h_aa + (size_t)b * M_M * XDIM + half * 32;
        for (int i = tid; i < M_M * 32; i += 256) {
            int m = i >> 5, oo = i & 31;
            float v = 0.f;
            #pragma unroll
            for (int gg = 0; gg < 8; ++gg) v += aa8[gg][m][oo];
            ob[m * XDIM + oo] = v;
        }
    } else {
        int b = bx - 2 * B_G;
        const float* ab = aaf + (size_t)b * M_M * AAF;
        float* ob = h_aa + (size_t)b * M_M * XDIM + H2C;
        for (int i = tid; i < M_M * AAF; i += 256) {
            int m = i / AAF, j = i - m * AAF;
            ob[m * XDIM + j] = ab[i];
        }
    }
}

// ---------------------------------------------------------------------------
// Amino-graph gcn_norm + dst-sorted CSR build (tiny, 1 block)
// ---------------------------------------------------------------------------
__global__ void aa_norm_kernel(const int* __restrict__ aei,
                               int* __restrict__ aa_off,
                               int* __restrict__ aa_src,
                               float* __restrict__ aa_nrm)
{
    __shared__ int   sdeg[M_M];
    __shared__ int   scur[M_M];
    __shared__ float sdinv[M_M];
    __shared__ int   soff[M_M + 1];
    int tid = threadIdx.x;
    if (tid < M_M) { sdeg[tid] = 0; scur[tid] = 0; }
    __syncthreads();
    if (tid < EA_E) atomicAdd(&sdeg[aei[EA_E + tid]], 1);
    __syncthreads();
    if (tid < M_M) {
        float dv = (float)sdeg[tid];
        sdinv[tid] = (dv > 0.f) ? (1.f / sqrtf(fmaxf(dv, 1.f))) : 0.f;
    }
    __syncthreads();
    if (tid == 0) {
        soff[0] = 0;
        for (int m = 0; m < M_M; ++m) soff[m + 1] = soff[m] + sdeg[m];
    }
    __syncthreads();
    if (tid < EA_E) {
        int ss = aei[tid], dd = aei[EA_E + tid];
        int pos = atomicAdd(&scur[dd], 1);
        int idx = soff[dd] + pos;
        aa_src[idx] = ss;
        aa_nrm[idx] = sdinv[ss] * sdinv[dd];
    }
    if (tid < M_M + 1) aa_off[tid] = soff[tid];
}

// ---------------------------------------------------------------------------
// Batched root GEMM, 4x8 tile, W chunk-staged in LDS (R18 arma lesson: in-loop
// global W loads at ~200cyc L2 latency were the limiter, VALUBusy 27%).
// 5 chunks of 32 k-rows, zero-padded so boundary chunk runs full 32 steps.
// LDS: x0 42 KB + Wlds 16.9 KB = 59 KB -> 2 blocks/CU.
// ---------------------------------------------------------------------------
__global__ __launch_bounds__(256) void rc_gemm(
    const float* __restrict__ h_aa, const float* __restrict__ init_w,
    const float* __restrict__ root_w, float* __restrict__ RC)
{
    __shared__ float x0[MPAD][XP];     // 42 KB (rows>=M_M and cols>=XDIM are 0)
    __shared__ float Wlds[32][GP];     // 16.9 KB, current 32-k-row chunk
    int b = blockIdx.x / NS, s = blockIdx.x % NS;
    int tid = threadIdx.x;
    int oi = tid & 15, mi = tid >> 4;
    int ob = oi * 8;
    const float* xb = h_aa + (size_t)b * M_M * XDIM;
    for (int i = tid; i < MPAD * XP; i += 256) {
        int m = i / XP, f = i - m * XP;
        x0[m][f] = (m < M_M && f < XDIM) ? xb[m * XDIM + f] : 0.f;
    }
    const float* W = (s < K_ST) ? (init_w + (size_t)s * XDIM * G_DIM)
                                : (root_w + (size_t)(s - K_ST) * XDIM * G_DIM);
    float4 acc[4][2];
    #pragma unroll
    for (int r = 0; r < 4; ++r) {
        acc[r][0] = make_float4(0.f,0.f,0.f,0.f);
        acc[r][1] = make_float4(0.f,0.f,0.f,0.f);
    }
    constexpr int NCHUNK = (XDIM + 31) / 32;   // 5
    for (int c = 0; c < NCHUNK; ++c) {
        int k0 = c * 32;
        __syncthreads();   // previous chunk's reads complete (and x0 ready at c=0)
        #pragma unroll
        for (int i = 0; i < 4; ++i) {
            int flat = (tid + i * 256) * 4;       // 0..16380
            int row = flat >> 7, col = flat & 127;
            int k = k0 + row;
            float4 v = (k < XDIM) ? *(const float4*)(W + (size_t)k * G_DIM + col)
                                  : make_float4(0.f, 0.f, 0.f, 0.f);
            *(float4*)&Wlds[row][col] = v;
        }
        __syncthreads();
        #pragma unroll
        for (int pp = 0; pp < 32; pp += 4) {
            float4 wv[4][2];
            #pragma unroll
            for (int q = 0; q < 4; ++q) {
                wv[q][0] = *(const float4*)&Wlds[pp + q][ob];
                wv[q][1] = *(const float4*)&Wlds[pp + q][ob + 4];
            }
            #pragma unroll
            for (int r = 0; r < 4; ++r) {
                float4 xv = *(const float4*)&x0[mi * 4 + r][k0 + pp];
                #pragma unroll
                for (int hh = 0; hh < 2; ++hh) {
                    f4fma(acc[r][hh], xv.x, wv[0][hh]);
                    f4fma(acc[r][hh], xv.y, wv[1][hh]);
                    f4fma(acc[r][hh], xv.z, wv[2][hh]);
                    f4fma(acc[r][hh], xv.w, wv[3][hh]);
                }
            }
        }
    }
    float* op = RC + ((size_t)(b * NS + s)) * M_M * G_DIM;
    #pragma unroll
    for (int r = 0; r < 4; ++r) {
        int m = mi * 4 + r;
        if (m < M_M) {
            float* pp = op + (size_t)m * G_DIM + ob;
            *(float4*)pp       = acc[r][0];
            *(float4*)(pp + 4) = acc[r][1];
        }
    }
}

// ---------------------------------------------------------------------------
// ARMA recurrence: one block per (b,k). 512 threads, 2x8 tile, W bulk-staged
// into LDS per t-step (R18). LDS 135 KB -> 1 block/CU.
// ---------------------------------------------------------------------------
__global__ __launch_bounds__(512) void arma_iter(
    const float* __restrict__ RC, const float* __restrict__ arma_w,
    const float* __restrict__ arma_bias,
    const int* __restrict__ aa_off, const int* __restrict__ aa_src,
    const float* __restrict__ aa_nrm, float* __restrict__ gfull)
{
    __shared__ float Abuf[MPAD][GP];   // 33.8 KB
    __shared__ float Bbuf[MPAD][GP];   // 33.8 KB
    __shared__ float Wlds[G_DIM][GP];  // 67.6 KB
    __shared__ int   s_off[M_M + 1];
    __shared__ int   s_src[EA_E];
    __shared__ float s_nrm[EA_E];
    int b = blockIdx.x / K_ST, k = blockIdx.x % K_ST;
    int tid = threadIdx.x;
    int oi = tid & 15;
    int mi = tid >> 4;
    int ob = oi * 8;
    const float* rcb = RC + (size_t)b * NS * M_M * G_DIM;

    if (tid < M_M + 1) s_off[tid] = aa_off[tid];
    if (tid < EA_E) { s_src[tid] = aa_src[tid]; s_nrm[tid] = aa_nrm[tid]; }

    for (int i = tid; i < MPAD * G_DIM; i += 512) {
        int m = i >> 7, o = i & 127;
        Abuf[m][o] = (m < M_M) ? rcb[(size_t)k * M_M * G_DIM + i] : 0.f;
        Bbuf[m][o] = 0.f;
    }
    __syncthreads();

    for (int t = 0; t < T_L; ++t) {
        if (t > 0) {
            const float* aw = arma_w + ((size_t)(t-1) * K_ST + k) * G_DIM * G_DIM;
            #pragma unroll
            for (int i = 0; i < 8; ++i) {
                int idx = (tid + i * 512) * 4;
                int row = idx >> 7, col = idx & 127;
                *(float4*)&Wlds[row][col] = *(const float4*)(aw + idx);
            }
            __syncthreads();
            float4 acc[2][2];
            #pragma unroll
            for (int r = 0; r < 2; ++r) {
                acc[r][0] = make_float4(0.f,0.f,0.f,0.f);
                acc[r][1] = make_float4(0.f,0.f,0.f,0.f);
            }
            for (int p = 0; p < G_DIM; p += 4) {
                float4 wv[4][2];
                #pragma unroll
                for (int q = 0; q < 4; ++q) {
                    wv[q][0] = *(const float4*)&Wlds[p + q][ob];
                    wv[q][1] = *(const float4*)&Wlds[p + q][ob + 4];
                }
                #pragma unroll
                for (int r = 0; r < 2; ++r) {
                    float4 xv = *(const float4*)&Bbuf[mi * 2 + r][p];
                    #pragma unroll
                    for (int hh = 0; hh < 2; ++hh) {
                        f4fma(acc[r][hh], xv.x, wv[0][hh]);
                        f4fma(acc[r][hh], xv.y, wv[1][hh]);
                        f4fma(acc[r][hh], xv.z, wv[2][hh]);
                        f4fma(acc[r][hh], xv.w, wv[3][hh]);
                    }
                }
            }
            __syncthreads();
            #pragma unroll
            for (int r = 0; r < 2; ++r) {
                float* apr = &Abuf[mi * 2 + r][ob];
                *(float4*)apr       = acc[r][0];
                *(float4*)(apr + 4) = acc[r][1];
            }
            __syncthreads();
        }
        const float* rct = rcb + (size_t)(K_ST + t * K_ST + k) * M_M * G_DIM;
        const float* bb  = arma_bias + ((size_t)t * K_ST + k) * G_DIM;
        float4 bias0 = *(const float4*)(bb + ob);
        float4 bias1 = *(const float4*)(bb + ob + 4);
        #pragma unroll
        for (int r = 0; r < 2; ++r) {
            int m = mi * 2 + r;
            if (m < M_M) {
                const float* rr = rct + (size_t)m * G_DIM + ob;
                float4 v0 = bias0, v1 = bias1;
                f4add(v0, *(const float4*)rr);
                f4add(v1, *(const float4*)(rr + 4));
                int j0 = s_off[m], j1 = s_off[m + 1];
                for (int j = j0; j < j1; ++j) {
                    float nv = s_nrm[j];
                    const float* ap = &Abuf[s_src[j]][ob];
                    float4 a0 = *(const float4*)ap;
                    float4 a1 = *(const float4*)(ap + 4);
                    f4fma(v0, nv, a0);
                    f4fma(v1, nv, a1);
                }
                f4relu(v0);
                f4relu(v1);
                float* bp = &Bbuf[m][ob];
                *(float4*)bp       = v0;
                *(float4*)(bp + 4) = v1;
            }
        }
        __syncthreads();
    }
    float* gb = gfull + ((size_t)(b * K_ST + k)) * M_M * G_DIM;
    for (int i = tid; i < M_M * G_DIM; i += 512) {
        int m = i >> 7, o = i & 127;
        gb[i] = Bbuf[m][o];
    }
}

// ---------------------------------------------------------------------------
// Mean over K, amino attention readout, MLP head. One block per graph.
// ---------------------------------------------------------------------------
__global__ __launch_bounds__(128) void aa_readout_mlp(
    const float* __restrict__ gfull, const float* __restrict__ wa,
    const float* __restrict__ ba,
    const float* __restrict__ W1, const float* __restrict__ b1,
    const float* __restrict__ W2, const float* __restrict__ b2,
    const float* __restrict__ W3, const float* __restrict__ b3,
    const float* __restrict__ W4, const float* __restrict__ b4,
    float* __restrict__ out)
{
    __shared__ float g[M_M][G_DIM + 1];
    __shared__ float s2[M_M];
    __shared__ float p[G_DIM];
    __shared__ float r1[64], r2[32], r3[16];
    int b = blockIdx.x, tid = threadIdx.x;
    const float* g0 = gfull + (size_t)b * K_ST * M_M * G_DIM;
    for (int i = tid; i < M_M * G_DIM; i += 128) {
        int m = i >> 7, o = i & 127;
        g[m][o] = (g0[i] + g0[M_M*G_DIM + i] + g0[2*M_M*G_DIM + i]) * (1.f/3.f);
    }
    __syncthreads();
    if (tid < M_M) {
        float sv = ba[0];
        for (int o = 0; o < G_DIM; ++o) sv += g[tid][o] * wa[o];
        s2[tid] = sv;
    }
    __syncthreads();
    if (tid == 0) {
        float mx = -1e30f;
        for (int m = 0; m < M_M; ++m) mx = fmaxf(mx, s2[m]);
        float den = 0.f;
        for (int m = 0; m < M_M; ++m) den += expf(s2[m] - mx);
        float inv = 1.f / den;
        for (int m = 0; m < M_M; ++m) s2[m] = expf(s2[m] - mx) * inv;
    }
    __syncthreads();
    {
        float pv = 0.f;
        for (int m = 0; m < M_M; ++m) pv += g[m][tid] * s2[m];
        p[tid] = pv;
    }
    __syncthreads();
    if (tid < 64) {
        float v = b1[tid];
        for (int i = 0; i < 128; ++i) v += p[i] * W1[i * 64 + tid];
        r1[tid] = fmaxf(v, 0.f);
    }
    __syncthreads();
    if (tid < 32) {
        float v = b2[tid];
        for (int i = 0; i < 64; ++i) v += r1[i] * W2[i * 32 + tid];
        r2[tid] = fmaxf(v, 0.f);
    }
    __syncthreads();
    if (tid < 16) {
        float v = b3[tid];
        for (int i = 0; i < 32; ++i) v += r2[i] * W3[i * 16 + tid];
        r3[tid] = fmaxf(v, 0.f);
    }
    __syncthreads();
    if (tid == 0) {
        float v = b4[0];
        for (int i = 0; i < 16; ++i) v += r3[i] * W4[i];
        out[b] = v;
    }
}

// ---------------------------------------------------------------------------
extern "C" void kernel_launch(void* const* d_in, const int* in_sizes, int n_in,
                              void* d_out, int out_size, void* d_ws, size_t ws_size,
                              hipStream_t stream)
{
    (void)in_sizes; (void)n_in; (void)out_size; (void)ws_size;
    const float* x            = (const float*)d_in[0];
    const float* edge_attr    = (const float*)d_in[1];
    const float* aa_features  = (const float*)d_in[2];
    const int*   edge_index   = (const int*)  d_in[3];
    const int*   mono_labels  = (const int*)  d_in[4];
    const int*   amino_ei     = (const int*)  d_in[5];
    const float* W_e1 = (const float*)d_in[6];
    const float* b_e1 = (const float*)d_in[7];
    const float* root1= (const float*)d_in[8];
    const float* bias1= (const float*)d_in[9];
    const float* W_e2 = (const float*)d_in[10];
    const float* b_e2 = (const float*)d_in[11];
    const float* root2= (const float*)d_in[12];
    const float* bias2= (const float*)d_in[13];
    const float* Wa_atom = (const float*)d_in[14];
    const float* ba_atom = (const float*)d_in[15];
    const float* arma_init_w = (const float*)d_in[16];
    const float* arma_w      = (const float*)d_in[17];
    const float* arma_root_w = (const float*)d_in[18];
    const float* arma_bias   = (const float*)d_in[19];
    const float* Wa_aa = (const float*)d_in[20];
    const float* ba_aa = (const float*)d_in[21];
    const float* W1 = (const float*)d_in[22];
    const float* b1 = (const float*)d_in[23];
    const float* W2 = (const float*)d_in[24];
    const float* b2 = (const float*)d_in[25];
    const float* W3 = (const float*)d_in[26];
    const float* b3 = (const float*)d_in[27];
    const float* W4 = (const float*)d_in[28];
    const float* b4 = (const float*)d_in[29];

    float* ws = (float*)d_ws;
    float* h1    = ws;                                   // N*32
    float* h2    = h1   + (size_t)N_ATOMS * H1C;         // N*64
    float* h_aa  = h2   + (size_t)N_ATOMS * H2C;         // B*M*159
    float* sc    = h_aa + (size_t)B_G * M_M * XDIM;      // B*NPG (scores)
    int*   aa_off = (int*)(sc + (size_t)B_G * NPG);      // M+1
    int*   aa_src = aa_off + (M_M + 1);                  // EA
    float* aa_nrm = (float*)(aa_src + EA_E);             // EA
    int*   deg_off = (int*)(aa_nrm + EA_E);              // N+1
    int*   cursor  = deg_off + (N_ATOMS + 1);            // N (adjacent -> one memset)
    int*   order   = cursor + N_ATOMS;                   // E
    int*   bsum    = order + E_EDGES;                    // NSB
    int*   bpre    = bsum + 256;                         // NSB
    float* RC    = (float*)(bpre + 256);                 // B*21*M*128 (26.9 MB)
    float* gfull = RC + (size_t)B_G * NS * M_M * G_DIM;  // B*3*M*128
    float* msg   = RC;   // alias: msg dead before rc_gemm writes RC

    (void)hipMemsetAsync(deg_off, 0, (2 * N_ATOMS + 1) * sizeof(int), stream);

    int eblocks = (E_EDGES + 255) / 256;
    int mblocks = (E_EDGES + 63) / 64;    // MFMA edge kernels: 64 edges/block

    // CSR build (3-phase parallel scan)
    deg_count<<<eblocks, 256, 0, stream>>>(edge_index, deg_off);
    scan_part<<<NSB, 256, 0, stream>>>(deg_off, bsum);
    scan_mid<<<1, 256, 0, stream>>>(bsum, bpre);
    scan_out<<<NSB, 256, 0, stream>>>(deg_off, bpre);
    fill_order<<<eblocks, 256, 0, stream>>>(edge_index, deg_off, cursor, order);

    // conv1 (MFMA, bf16 inputs / fp32 accumulate)
    edge_msg_mfma<DIN, H1C><<<mblocks, 256, 0, stream>>>(
        x, edge_attr, edge_index, W_e1, b_e1, msg);
    gather_update<DIN, H1C><<<(N_ATOMS + 7) / 8, 256, 0, stream>>>(
        msg, deg_off, order, x, root1, bias1, h1);
    // conv2 (MFMA)
    edge_msg_mfma<H1C, H2C><<<mblocks, 256, 0, stream>>>(
        h1, edge_attr, edge_index, W_e2, b_e2, msg);
    gather_update<H1C, H2C><<<(N_ATOMS + 3) / 4, 256, 0, stream>>>(
        msg, deg_off, order, h1, root2, bias2, h2);

    // atom attention readout (softmax fused into aggregate)
    atom_score<<<(N_ATOMS + 127) / 128, 256, 0, stream>>>(h2, Wa_atom, ba_atom, sc);
    atom_aggregate<<<3 * B_G, 256, 0, stream>>>(h2, sc, mono_labels, aa_features, h_aa);

    aa_norm_kernel<<<1, 128, 0, stream>>>(amino_ei, aa_off, aa_src, aa_nrm);
    rc_gemm<<<B_G * NS, 256, 0, stream>>>(h_aa, arma_init_w, arma_root_w, RC);
    arma_iter<<<B_G * K_ST, 512, 0, stream>>>(RC, arma_w, arma_bias,
                                              aa_off, aa_src, aa_nrm, gfull);
    aa_readout_mlp<<<B_G, 128, 0, stream>>>(gfull, Wa_aa, ba_aa, W1, b1, W2, b2, W3, b3, W4, b4,
                                            (float*)d_out);
}

// Round 20
// 427.163 us; speedup vs baseline: 1.3314x; 1.1225x over previous
//
#include <hip/hip_runtime.h>
#include <math.h>

#define N_ATOMS 50000
#define E_EDGES 100000
#define B_G     50
#define M_M     50
#define NPG     1000
#define DIN     32
#define H1C     32
#define H2C     64
#define DEC     16
#define AAF     95
#define G_DIM   128
#define K_ST    3
#define T_L     6
#define EA_E    98
#define XDIM    159          // H2 + AAF
#define NS      21           // K + T*K weight slices
#define MPAD    64           // M padded for regular tiling
#define GP      132          // G_DIM padded
#define KP2     168          // K padded for bf16 GEMM operands (159 -> 168, 16B mult)
#define NSB     ((N_ATOMS + 255) / 256)   // 196 scan blocks

typedef __attribute__((ext_vector_type(8))) short bf16x8;
typedef __attribute__((ext_vector_type(4))) float f32x4;

__device__ __forceinline__ short f2bf(float f) {
    unsigned int u = __float_as_uint(f);
    unsigned int r = (u + 0x7FFFu + ((u >> 16) & 1u)) >> 16;   // RNE
    return (short)r;
}
__device__ __forceinline__ float bf2f(short b) {
    return __uint_as_float(((unsigned int)(unsigned short)b) << 16);
}

__device__ __forceinline__ void f4fma(float4& d, float s, const float4& v) {
    d.x += s * v.x; d.y += s * v.y; d.z += s * v.z; d.w += s * v.w;
}
__device__ __forceinline__ void f4add(float4& d, const float4& v) {
    d.x += v.x; d.y += v.y; d.z += v.z; d.w += v.w;
}
__device__ __forceinline__ void f4relu(float4& d) {
    d.x = fmaxf(d.x, 0.f); d.y = fmaxf(d.y, 0.f);
    d.z = fmaxf(d.z, 0.f); d.w = fmaxf(d.w, 0.f);
}

// ---------------------------------------------------------------------------
// CSR build: degree count -> 3-phase parallel scan -> bucket fill
// ---------------------------------------------------------------------------
__global__ __launch_bounds__(256) void deg_count(const int* __restrict__ eidx,
                                                 int* __restrict__ deg)
{
    int e = blockIdx.x * 256 + threadIdx.x;
    if (e >= E_EDGES) return;
    atomicAdd(&deg[eidx[E_EDGES + e]], 1);
}

__global__ __launch_bounds__(256) void scan_part(const int* __restrict__ deg,
                                                 int* __restrict__ bsum)
{
    __shared__ int tmp[256];
    int tid = threadIdx.x;
    int n = blockIdx.x * 256 + tid;
    tmp[tid] = (n < N_ATOMS) ? deg[n] : 0;
    __syncthreads();
    for (int off = 128; off > 0; off >>= 1) {
        if (tid < off) tmp[tid] += tmp[tid + off];
        __syncthreads();
    }
    if (tid == 0) bsum[blockIdx.x] = tmp[0];
}

__global__ __launch_bounds__(256) void scan_mid(const int* __restrict__ bsum,
                                                int* __restrict__ bpre)
{
    __shared__ int tmp[256];
    int tid = threadIdx.x;
    int v = (tid < NSB) ? bsum[tid] : 0;
    tmp[tid] = v;
    __syncthreads();
    for (int off = 1; off < 256; off <<= 1) {
        int t = tmp[tid];
        int add = (tid >= off) ? tmp[tid - off] : 0;
        __syncthreads();
        tmp[tid] = t + add;
        __syncthreads();
    }
    if (tid < NSB) bpre[tid] = tmp[tid] - v;   // exclusive
}

__global__ __launch_bounds__(256) void scan_out(int* __restrict__ deg_off,
                                                const int* __restrict__ bpre)
{
    __shared__ int tmp[256];
    int tid = threadIdx.x;
    int n = blockIdx.x * 256 + tid;
    int v = (n < N_ATOMS) ? deg_off[n] : 0;
    tmp[tid] = v;
    __syncthreads();
    for (int off = 1; off < 256; off <<= 1) {
        int t = tmp[tid];
        int add = (tid >= off) ? tmp[tid - off] : 0;
        __syncthreads();
        tmp[tid] = t + add;
        __syncthreads();
    }
    int incl = tmp[tid];
    int base = bpre[blockIdx.x];
    if (n < N_ATOMS) deg_off[n] = base + incl - v;
    if (n == N_ATOMS - 1) deg_off[N_ATOMS] = base + incl;
}

__global__ __launch_bounds__(256) void fill_order(const int* __restrict__ eidx,
                                                  const int* __restrict__ off,
                                                  int* __restrict__ cursor,
                                                  int* __restrict__ order)
{
    int e = blockIdx.x * 256 + threadIdx.x;
    if (e >= E_EDGES) return;
    int d = eidx[E_EDGES + e];
    int pos = atomicAdd(&cursor[d], 1);
    order[off[d] + pos] = e;
}

// ---------------------------------------------------------------------------
// MFMA edge message kernel (R16, verified absmax 9.5e-7).
// ---------------------------------------------------------------------------
template<int FIN, int FOUT>
__global__ __launch_bounds__(256, 2) void edge_msg_mfma(
    const float* __restrict__ h, const float* __restrict__ ea,
    const int* __restrict__ eidx, const float* __restrict__ We,
    const float* __restrict__ be, float* __restrict__ msg)
{
    static_assert(FIN == 32, "K mapping assumes FIN==32");
    constexpr int K0  = DEC * FIN;        // 512
    constexpr int KS  = (K0 + FIN) / 32;  // 17
    constexpr int WTP = 552;
    constexpr int NT  = FOUT / 16;
    __shared__ short Wt[FOUT][WTP];
    __shared__ short hA[64][40];
    __shared__ short eaA[64][16];
    int tid = threadIdx.x;
    int ebase = blockIdx.x * 64;

    for (int i = tid; i < DEC * FIN * FOUT; i += 256) {
        int o  = i % FOUT;
        int fk = i / FOUT;
        Wt[o][fk] = f2bf(We[i]);
    }
    for (int i = tid; i < FIN * FOUT; i += 256) {
        int o = i % FOUT, ff = i / FOUT;
        Wt[o][K0 + ff] = f2bf(be[i]);
    }
    for (int i = tid; i < 64 * FIN; i += 256) {
        int r = i / FIN, f = i % FIN;
        int e = ebase + r; int es = (e < E_EDGES) ? e : 0;
        int s = eidx[es];
        hA[r][f] = f2bf(h[(size_t)s * FIN + f]);
    }
    for (int i = tid; i < 64 * DEC; i += 256) {
        int r = i / DEC, d = i % DEC;
        int e = ebase + r; int es = (e < E_EDGES) ? e : 0;
        eaA[r][d] = f2bf(ea[(size_t)es * DEC + d]);
    }
    __syncthreads();

    int lane = tid & 63;
    int wave = tid >> 6;
    int l16  = lane & 15;
    int quad = lane >> 4;

    float hf[8];
    {
        const short* hp = &hA[wave * 16 + l16][quad * 8];
        #pragma unroll
        for (int j = 0; j < 8; ++j) hf[j] = bf2f(hp[j]);
    }
    float eaf[16];
    {
        const short* ep = &eaA[wave * 16 + l16][0];
        #pragma unroll
        for (int d = 0; d < 16; ++d) eaf[d] = bf2f(ep[d]);
    }

    f32x4 acc[NT];
    #pragma unroll
    for (int nt = 0; nt < NT; ++nt) acc[nt] = (f32x4){0.f, 0.f, 0.f, 0.f};

    #pragma unroll
    for (int ks = 0; ks < KS; ++ks) {
        float fac = (ks < DEC) ? eaf[ks] : 1.0f;
        bf16x8 a;
        #pragma unroll
        for (int j = 0; j < 8; ++j) a[j] = f2bf(fac * hf[j]);
        #pragma unroll
        for (int nt = 0; nt < NT; ++nt) {
            const bf16x8 b = *(const bf16x8*)&Wt[nt * 16 + l16][ks * 32 + quad * 8];
            acc[nt] = __builtin_amdgcn_mfma_f32_16x16x32_bf16(a, b, acc[nt], 0, 0, 0);
        }
    }
    #pragma unroll
    for (int nt = 0; nt < NT; ++nt) {
        #pragma unroll
        for (int r = 0; r < 4; ++r) {
            int e = ebase + wave * 16 + quad * 4 + r;
            if (e < E_EDGES)
                msg[(size_t)e * FOUT + nt * 16 + l16] = acc[nt][r];
        }
    }
}

// ---------------------------------------------------------------------------
// Gather + node update fused
// ---------------------------------------------------------------------------
template<int FIN, int FOUT>
__global__ __launch_bounds__(256) void gather_update(
    const float* __restrict__ msg, const int* __restrict__ off,
    const int* __restrict__ order, const float* __restrict__ hin,
    const float* __restrict__ root, const float* __restrict__ bias,
    float* __restrict__ hout)
{
    constexpr int NPB = 256 / FOUT;
    __shared__ float rlds[FIN][FOUT];
    __shared__ float hlds[NPB][FIN];
    int tid = threadIdx.x;
    for (int i = tid; i < FIN * FOUT / 4; i += 256) {
        *(float4*)&rlds[0][i * 4] = *(const float4*)(root + i * 4);
    }
    int nb = blockIdx.x * NPB;
    for (int i = tid; i < NPB * FIN; i += 256) {
        int ln = i / FIN, f = i % FIN;
        int n = nb + ln;
        hlds[ln][f] = (n < N_ATOMS) ? hin[(size_t)n * FIN + f] : 0.f;
    }
    __syncthreads();

    int ln = tid / FOUT, o = tid % FOUT;
    int n = nb + ln;
    if (n >= N_ATOMS) return;
    float acc = bias[o];
    #pragma unroll 8
    for (int f = 0; f < FIN; ++f) acc += hlds[ln][f] * rlds[f][o];
    int j0 = off[n], j1 = off[n + 1];
    for (int j = j0; j < j1; ++j) {
        int e = order[j];
        acc += msg[(size_t)e * FOUT + o];
    }
    hout[(size_t)n * FOUT + o] = fmaxf(acc, 0.f);
}

// ---------------------------------------------------------------------------
// Atom attention: atom_score then atom_aggregate (softmax fused in-block)
// ---------------------------------------------------------------------------
__global__ __launch_bounds__(256) void atom_score(
    const float* __restrict__ h2, const float* __restrict__ wa,
    const float* __restrict__ ba, float* __restrict__ sc)
{
    __shared__ float hl[128][65];
    int nb = blockIdx.x * 128;
    int tid = threadIdx.x;
    for (int i = tid; i < 128 * 16; i += 256) {
        int r = i >> 4, c4 = i & 15;
        int n = nb + r;
        float4 v = (n < N_ATOMS) ? *(const float4*)(h2 + (size_t)n * H2C + c4 * 4)
                                 : make_float4(0.f, 0.f, 0.f, 0.f);
        *(float4*)&hl[r][c4 * 4] = v;
    }
    __syncthreads();
    if (tid < 128) {
        int n = nb + tid;
        if (n < N_ATOMS) {
            float sv = ba[0];
            #pragma unroll 8
            for (int o = 0; o < H2C; ++o) sv += hl[tid][o] * wa[o];
            sc[n] = sv;
        }
    }
}

__global__ __launch_bounds__(256) void atom_aggregate(
    const float* __restrict__ h2, const float* __restrict__ sc,
    const int* __restrict__ labels, const float* __restrict__ aaf,
    float* __restrict__ h_aa)
{
    int bx = blockIdx.x, tid = threadIdx.x;
    if (bx < 2 * B_G) {
        __shared__ float aa8[8][M_M][32];   // 51.2 KB
        __shared__ float red[256];
        int b = bx >> 1, half = bx & 1;
        int g = tid >> 5, o = tid & 31;
        const float* sb = sc + (size_t)b * NPG;
        float lmax = -1e30f;
        for (int n = tid; n < NPG; n += 256) lmax = fmaxf(lmax, sb[n]);
        red[tid] = lmax;
        __syncthreads();
        for (int off = 128; off > 0; off >>= 1) {
            if (tid < off) red[tid] = fmaxf(red[tid], red[tid + off]);
            __syncthreads();
        }
        float mx = red[0];
        __syncthreads();
        float lsum = 0.f;
        for (int n = tid; n < NPG; n += 256) lsum += expf(sb[n] - mx);
        red[tid] = lsum;
        __syncthreads();
        for (int off = 128; off > 0; off >>= 1) {
            if (tid < off) red[tid] += red[tid + off];
            __syncthreads();
        }
        float inv = 1.f / red[0];
        __syncthreads();
        for (int i = tid; i < 8 * M_M * 32; i += 256) ((float*)aa8)[i] = 0.f;
        __syncthreads();
        const float* hb = h2 + (size_t)b * NPG * H2C + half * 32;
        for (int n = g; n < NPG; n += 8) {
            int lbl = labels[b * NPG + n];
            float w = expf(sb[n] - mx) * inv;
            float hvv = hb[(size_t)n * H2C + o];
            aa8[g][lbl][o] += hvv * w;
        }
        __syncthreads();
        float* ob = h_aa + (size_t)b * M_M * XDIM + half * 32;
        for (int i = tid; i < M_M * 32; i += 256) {
            int m = i >> 5, oo = i & 31;
            float v = 0.f;
            #pragma unroll
            for (int gg = 0; gg < 8; ++gg) v += aa8[gg][m][oo];
            ob[m * XDIM + oo] = v;
        }
    } else {
        int b = bx - 2 * B_G;
        const float* ab = aaf + (size_t)b * M_M * AAF;
        float* ob = h_aa + (size_t)b * M_M * XDIM + H2C;
        for (int i = tid; i < M_M * AAF; i += 256) {
            int m = i / AAF, j = i - m * AAF;
            ob[m * XDIM + j] = ab[i];
        }
    }
}

// ---------------------------------------------------------------------------
// Amino-graph gcn_norm + dst-sorted CSR build (tiny, 1 block)
// ---------------------------------------------------------------------------
__global__ void aa_norm_kernel(const int* __restrict__ aei,
                               int* __restrict__ aa_off,
                               int* __restrict__ aa_src,
                               float* __restrict__ aa_nrm)
{
    __shared__ int   sdeg[M_M];
    __shared__ int   scur[M_M];
    __shared__ float sdinv[M_M];
    __shared__ int   soff[M_M + 1];
    int tid = threadIdx.x;
    if (tid < M_M) { sdeg[tid] = 0; scur[tid] = 0; }
    __syncthreads();
    if (tid < EA_E) atomicAdd(&sdeg[aei[EA_E + tid]], 1);
    __syncthreads();
    if (tid < M_M) {
        float dv = (float)sdeg[tid];
        sdinv[tid] = (dv > 0.f) ? (1.f / sqrtf(fmaxf(dv, 1.f))) : 0.f;
    }
    __syncthreads();
    if (tid == 0) {
        soff[0] = 0;
        for (int m = 0; m < M_M; ++m) soff[m + 1] = soff[m] + sdeg[m];
    }
    __syncthreads();
    if (tid < EA_E) {
        int ss = aei[tid], dd = aei[EA_E + tid];
        int pos = atomicAdd(&scur[dd], 1);
        int idx = soff[dd] + pos;
        aa_src[idx] = ss;
        aa_nrm[idx] = sdinv[ss] * sdinv[dd];
    }
    if (tid < M_M + 1) aa_off[tid] = soff[tid];
}

// ---------------------------------------------------------------------------
// RC GEMM prep: bf16-transpose all 21 W slices once (shared by 50 graphs) and
// bf16-convert h_aa once (shared by 21 slices). Wtb[s][n][k], x0b[b][m][k],
// K padded to KP2=168 (zeros).
// ---------------------------------------------------------------------------
__global__ __launch_bounds__(256) void prep_wt(
    const float* __restrict__ init_w, const float* __restrict__ root_w,
    short* __restrict__ Wtb)
{
    int idx = blockIdx.x * 256 + threadIdx.x;
    if (idx >= NS * XDIM * G_DIM) return;
    int s = idx / (XDIM * G_DIM);
    int rem = idx - s * XDIM * G_DIM;
    int k = rem / G_DIM, n = rem - k * G_DIM;
    float v = (s < K_ST) ? init_w[idx]
                         : root_w[(size_t)(s - K_ST) * XDIM * G_DIM + rem];
    Wtb[(size_t)s * G_DIM * KP2 + n * KP2 + k] = f2bf(v);
}

__global__ __launch_bounds__(256) void prep_x0(
    const float* __restrict__ h_aa, short* __restrict__ x0b)
{
    int idx = blockIdx.x * 256 + threadIdx.x;
    if (idx >= B_G * MPAD * KP2) return;
    int b = idx / (MPAD * KP2);
    int rem = idx - b * MPAD * KP2;
    int m = rem / KP2, k = rem - m * KP2;
    float v = (m < M_M && k < XDIM) ? h_aa[((size_t)b * M_M + m) * XDIM + k] : 0.f;
    x0b[idx] = f2bf(v);
}

// ---------------------------------------------------------------------------
// MFMA rc_gemm: RC[b,s] = x0b[b] @ Wtb[s]^T-view, zero LDS, zero barriers.
// A/B frags straight from global (L2-hot). R19 showed the fp32 version was
// LDS-pipe-bound (12 b128 per 128 FMA, 4.5x oversubscribed, 5.4M conflicts).
// ---------------------------------------------------------------------------
__global__ __launch_bounds__(256) void rc_gemm_mfma(
    const short* __restrict__ x0b, const short* __restrict__ Wtb,
    float* __restrict__ RC)
{
    int b = blockIdx.x / NS, s = blockIdx.x % NS;
    int tid = threadIdx.x;
    int lane = tid & 63, wave = tid >> 6;
    int l16 = lane & 15, quad = lane >> 4;
    const short* xa = x0b + (size_t)b * MPAD * KP2 + (wave * 16 + l16) * KP2;
    const short* wb = Wtb + (size_t)s * G_DIM * KP2;

    f32x4 acc[8];
    #pragma unroll
    for (int nt = 0; nt < 8; ++nt) acc[nt] = (f32x4){0.f, 0.f, 0.f, 0.f};

    #pragma unroll
    for (int ks = 0; ks < 5; ++ks) {          // K = 160
        bf16x8 a = *(const bf16x8*)(xa + ks * 32 + quad * 8);
        #pragma unroll
        for (int nt = 0; nt < 8; ++nt) {
            bf16x8 bf = *(const bf16x8*)(wb + (nt * 16 + l16) * KP2 + ks * 32 + quad * 8);
            acc[nt] = __builtin_amdgcn_mfma_f32_16x16x32_bf16(a, bf, acc[nt], 0, 0, 0);
        }
    }
    float* op = RC + (size_t)(b * NS + s) * M_M * G_DIM;
    #pragma unroll
    for (int nt = 0; nt < 8; ++nt) {
        #pragma unroll
        for (int r = 0; r < 4; ++r) {
            int m = wave * 16 + quad * 4 + r;
            if (m < M_M)
                op[m * G_DIM + nt * 16 + l16] = acc[nt][r];
        }
    }
}

// ---------------------------------------------------------------------------
// ARMA recurrence: one block per (b,k). 512 threads, 2x8 tile, W bulk-staged
// into LDS per t-step (R18). LDS 135 KB -> 1 block/CU.
// ---------------------------------------------------------------------------
__global__ __launch_bounds__(512) void arma_iter(
    const float* __restrict__ RC, const float* __restrict__ arma_w,
    const float* __restrict__ arma_bias,
    const int* __restrict__ aa_off, const int* __restrict__ aa_src,
    const float* __restrict__ aa_nrm, float* __restrict__ gfull)
{
    __shared__ float Abuf[MPAD][GP];   // 33.8 KB
    __shared__ float Bbuf[MPAD][GP];   // 33.8 KB
    __shared__ float Wlds[G_DIM][GP];  // 67.6 KB
    __shared__ int   s_off[M_M + 1];
    __shared__ int   s_src[EA_E];
    __shared__ float s_nrm[EA_E];
    int b = blockIdx.x / K_ST, k = blockIdx.x % K_ST;
    int tid = threadIdx.x;
    int oi = tid & 15;
    int mi = tid >> 4;
    int ob = oi * 8;
    const float* rcb = RC + (size_t)b * NS * M_M * G_DIM;

    if (tid < M_M + 1) s_off[tid] = aa_off[tid];
    if (tid < EA_E) { s_src[tid] = aa_src[tid]; s_nrm[tid] = aa_nrm[tid]; }

    for (int i = tid; i < MPAD * G_DIM; i += 512) {
        int m = i >> 7, o = i & 127;
        Abuf[m][o] = (m < M_M) ? rcb[(size_t)k * M_M * G_DIM + i] : 0.f;
        Bbuf[m][o] = 0.f;
    }
    __syncthreads();

    for (int t = 0; t < T_L; ++t) {
        if (t > 0) {
            const float* aw = arma_w + ((size_t)(t-1) * K_ST + k) * G_DIM * G_DIM;
            #pragma unroll
            for (int i = 0; i < 8; ++i) {
                int idx = (tid + i * 512) * 4;
                int row = idx >> 7, col = idx & 127;
                *(float4*)&Wlds[row][col] = *(const float4*)(aw + idx);
            }
            __syncthreads();
            float4 acc[2][2];
            #pragma unroll
            for (int r = 0; r < 2; ++r) {
                acc[r][0] = make_float4(0.f,0.f,0.f,0.f);
                acc[r][1] = make_float4(0.f,0.f,0.f,0.f);
            }
            for (int p = 0; p < G_DIM; p += 4) {
                float4 wv[4][2];
                #pragma unroll
                for (int q = 0; q < 4; ++q) {
                    wv[q][0] = *(const float4*)&Wlds[p + q][ob];
                    wv[q][1] = *(const float4*)&Wlds[p + q][ob + 4];
                }
                #pragma unroll
                for (int r = 0; r < 2; ++r) {
                    float4 xv = *(const float4*)&Bbuf[mi * 2 + r][p];
                    #pragma unroll
                    for (int hh = 0; hh < 2; ++hh) {
                        f4fma(acc[r][hh], xv.x, wv[0][hh]);
                        f4fma(acc[r][hh], xv.y, wv[1][hh]);
                        f4fma(acc[r][hh], xv.z, wv[2][hh]);
                        f4fma(acc[r][hh], xv.w, wv[3][hh]);
                    }
                }
            }
            __syncthreads();
            #pragma unroll
            for (int r = 0; r < 2; ++r) {
                float* apr = &Abuf[mi * 2 + r][ob];
                *(float4*)apr       = acc[r][0];
                *(float4*)(apr + 4) = acc[r][1];
            }
            __syncthreads();
        }
        const float* rct = rcb + (size_t)(K_ST + t * K_ST + k) * M_M * G_DIM;
        const float* bb  = arma_bias + ((size_t)t * K_ST + k) * G_DIM;
        float4 bias0 = *(const float4*)(bb + ob);
        float4 bias1 = *(const float4*)(bb + ob + 4);
        #pragma unroll
        for (int r = 0; r < 2; ++r) {
            int m = mi * 2 + r;
            if (m < M_M) {
                const float* rr = rct + (size_t)m * G_DIM + ob;
                float4 v0 = bias0, v1 = bias1;
                f4add(v0, *(const float4*)rr);
                f4add(v1, *(const float4*)(rr + 4));
                int j0 = s_off[m], j1 = s_off[m + 1];
                for (int j = j0; j < j1; ++j) {
                    float nv = s_nrm[j];
                    const float* ap = &Abuf[s_src[j]][ob];
                    float4 a0 = *(const float4*)ap;
                    float4 a1 = *(const float4*)(ap + 4);
                    f4fma(v0, nv, a0);
                    f4fma(v1, nv, a1);
                }
                f4relu(v0);
                f4relu(v1);
                float* bp = &Bbuf[m][ob];
                *(float4*)bp       = v0;
                *(float4*)(bp + 4) = v1;
            }
        }
        __syncthreads();
    }
    float* gb = gfull + ((size_t)(b * K_ST + k)) * M_M * G_DIM;
    for (int i = tid; i < M_M * G_DIM; i += 512) {
        int m = i >> 7, o = i & 127;
        gb[i] = Bbuf[m][o];
    }
}

// ---------------------------------------------------------------------------
// Mean over K, amino attention readout, MLP head. One block per graph.
// ---------------------------------------------------------------------------
__global__ __launch_bounds__(128) void aa_readout_mlp(
    const float* __restrict__ gfull, const float* __restrict__ wa,
    const float* __restrict__ ba,
    const float* __restrict__ W1, const float* __restrict__ b1,
    const float* __restrict__ W2, const float* __restrict__ b2,
    const float* __restrict__ W3, const float* __restrict__ b3,
    const float* __restrict__ W4, const float* __restrict__ b4,
    float* __restrict__ out)
{
    __shared__ float g[M_M][G_DIM + 1];
    __shared__ float s2[M_M];
    __shared__ float p[G_DIM];
    __shared__ float r1[64], r2[32], r3[16];
    int b = blockIdx.x, tid = threadIdx.x;
    const float* g0 = gfull + (size_t)b * K_ST * M_M * G_DIM;
    for (int i = tid; i < M_M * G_DIM; i += 128) {
        int m = i >> 7, o = i & 127;
        g[m][o] = (g0[i] + g0[M_M*G_DIM + i] + g0[2*M_M*G_DIM + i]) * (1.f/3.f);
    }
    __syncthreads();
    if (tid < M_M) {
        float sv = ba[0];
        for (int o = 0; o < G_DIM; ++o) sv += g[tid][o] * wa[o];
        s2[tid] = sv;
    }
    __syncthreads();
    if (tid == 0) {
        float mx = -1e30f;
        for (int m = 0; m < M_M; ++m) mx = fmaxf(mx, s2[m]);
        float den = 0.f;
        for (int m = 0; m < M_M; ++m) den += expf(s2[m] - mx);
        float inv = 1.f / den;
        for (int m = 0; m < M_M; ++m) s2[m] = expf(s2[m] - mx) * inv;
    }
    __syncthreads();
    {
        float pv = 0.f;
        for (int m = 0; m < M_M; ++m) pv += g[m][tid] * s2[m];
        p[tid] = pv;
    }
    __syncthreads();
    if (tid < 64) {
        float v = b1[tid];
        for (int i = 0; i < 128; ++i) v += p[i] * W1[i * 64 + tid];
        r1[tid] = fmaxf(v, 0.f);
    }
    __syncthreads();
    if (tid < 32) {
        float v = b2[tid];
        for (int i = 0; i < 64; ++i) v += r1[i] * W2[i * 32 + tid];
        r2[tid] = fmaxf(v, 0.f);
    }
    __syncthreads();
    if (tid < 16) {
        float v = b3[tid];
        for (int i = 0; i < 32; ++i) v += r2[i] * W3[i * 16 + tid];
        r3[tid] = fmaxf(v, 0.f);
    }
    __syncthreads();
    if (tid == 0) {
        float v = b4[0];
        for (int i = 0; i < 16; ++i) v += r3[i] * W4[i];
        out[b] = v;
    }
}

// ---------------------------------------------------------------------------
extern "C" void kernel_launch(void* const* d_in, const int* in_sizes, int n_in,
                              void* d_out, int out_size, void* d_ws, size_t ws_size,
                              hipStream_t stream)
{
    (void)in_sizes; (void)n_in; (void)out_size; (void)ws_size;
    const float* x            = (const float*)d_in[0];
    const float* edge_attr    = (const float*)d_in[1];
    const float* aa_features  = (const float*)d_in[2];
    const int*   edge_index   = (const int*)  d_in[3];
    const int*   mono_labels  = (const int*)  d_in[4];
    const int*   amino_ei     = (const int*)  d_in[5];
    const float* W_e1 = (const float*)d_in[6];
    const float* b_e1 = (const float*)d_in[7];
    const float* root1= (const float*)d_in[8];
    const float* bias1= (const float*)d_in[9];
    const float* W_e2 = (const float*)d_in[10];
    const float* b_e2 = (const float*)d_in[11];
    const float* root2= (const float*)d_in[12];
    const float* bias2= (const float*)d_in[13];
    const float* Wa_atom = (const float*)d_in[14];
    const float* ba_atom = (const float*)d_in[15];
    const float* arma_init_w = (const float*)d_in[16];
    const float* arma_w      = (const float*)d_in[17];
    const float* arma_root_w = (const float*)d_in[18];
    const float* arma_bias   = (const float*)d_in[19];
    const float* Wa_aa = (const float*)d_in[20];
    const float* ba_aa = (const float*)d_in[21];
    const float* W1 = (const float*)d_in[22];
    const float* b1 = (const float*)d_in[23];
    const float* W2 = (const float*)d_in[24];
    const float* b2 = (const float*)d_in[25];
    const float* W3 = (const float*)d_in[26];
    const float* b3 = (const float*)d_in[27];
    const float* W4 = (const float*)d_in[28];
    const float* b4 = (const float*)d_in[29];

    float* ws = (float*)d_ws;
    float* h1    = ws;                                   // N*32
    float* h2    = h1   + (size_t)N_ATOMS * H1C;         // N*64
    float* h_aa  = h2   + (size_t)N_ATOMS * H2C;         // B*M*159
    float* sc    = h_aa + (size_t)B_G * M_M * XDIM;      // B*NPG (scores)
    int*   aa_off = (int*)(sc + (size_t)B_G * NPG);      // M+1
    int*   aa_src = aa_off + (M_M + 1);                  // EA
    float* aa_nrm = (float*)(aa_src + EA_E);             // EA
    int*   deg_off = (int*)(aa_nrm + EA_E);              // N+1
    int*   cursor  = deg_off + (N_ATOMS + 1);            // N (adjacent -> one memset)
    int*   order   = cursor + N_ATOMS;                   // E
    int*   bsum    = order + E_EDGES;                    // NSB
    int*   bpre    = bsum + 256;                         // NSB
    float* RC    = (float*)(bpre + 256);                 // B*21*M*128 (26.9 MB)
    float* gfull = RC + (size_t)B_G * NS * M_M * G_DIM;  // B*3*M*128
    short* Wtb   = (short*)((((uintptr_t)(gfull + (size_t)B_G * K_ST * M_M * G_DIM)) + 15)
                            & ~(uintptr_t)15);           // NS*128*168 bf16 (903 KB)
    short* x0b   = Wtb + (size_t)NS * G_DIM * KP2;       // B*64*168 bf16 (1.07 MB)
    float* msg   = RC;   // alias: msg dead before rc_gemm writes RC

    (void)hipMemsetAsync(deg_off, 0, (2 * N_ATOMS + 1) * sizeof(int), stream);

    int eblocks = (E_EDGES + 255) / 256;
    int mblocks = (E_EDGES + 63) / 64;    // MFMA edge kernels: 64 edges/block

    // CSR build (3-phase parallel scan)
    deg_count<<<eblocks, 256, 0, stream>>>(edge_index, deg_off);
    scan_part<<<NSB, 256, 0, stream>>>(deg_off, bsum);
    scan_mid<<<1, 256, 0, stream>>>(bsum, bpre);
    scan_out<<<NSB, 256, 0, stream>>>(deg_off, bpre);
    fill_order<<<eblocks, 256, 0, stream>>>(edge_index, deg_off, cursor, order);

    // W transpose/bf16 prep (independent of everything above)
    prep_wt<<<(NS * XDIM * G_DIM + 255) / 256, 256, 0, stream>>>(
        arma_init_w, arma_root_w, Wtb);

    // conv1 (MFMA, bf16 inputs / fp32 accumulate)
    edge_msg_mfma<DIN, H1C><<<mblocks, 256, 0, stream>>>(
        x, edge_attr, edge_index, W_e1, b_e1, msg);
    gather_update<DIN, H1C><<<(N_ATOMS + 7) / 8, 256, 0, stream>>>(
        msg, deg_off, order, x, root1, bias1, h1);
    // conv2 (MFMA)
    edge_msg_mfma<H1C, H2C><<<mblocks, 256, 0, stream>>>(
        h1, edge_attr, edge_index, W_e2, b_e2, msg);
    gather_update<H1C, H2C><<<(N_ATOMS + 3) / 4, 256, 0, stream>>>(
        msg, deg_off, order, h1, root2, bias2, h2);

    // atom attention readout (softmax fused into aggregate)
    atom_score<<<(N_ATOMS + 127) / 128, 256, 0, stream>>>(h2, Wa_atom, ba_atom, sc);
    atom_aggregate<<<3 * B_G, 256, 0, stream>>>(h2, sc, mono_labels, aa_features, h_aa);

    aa_norm_kernel<<<1, 128, 0, stream>>>(amino_ei, aa_off, aa_src, aa_nrm);
    prep_x0<<<(B_G * MPAD * KP2 + 255) / 256, 256, 0, stream>>>(h_aa, x0b);
    rc_gemm_mfma<<<B_G * NS, 256, 0, stream>>>(x0b, Wtb, RC);
    arma_iter<<<B_G * K_ST, 512, 0, stream>>>(RC, arma_w, arma_bias,
                                              aa_off, aa_src, aa_nrm, gfull);
    aa_readout_mlp<<<B_G, 128, 0, stream>>>(gfull, Wa_aa, ba_aa, W1, b1, W2, b2, W3, b3, W4, b4,
                                            (float*)d_out);
}

// Round 21
// 408.888 us; speedup vs baseline: 1.3909x; 1.0447x over previous
//
#include <hip/hip_runtime.h>
#include <math.h>

#define N_ATOMS 50000
#define E_EDGES 100000
#define B_G     50
#define M_M     50
#define NPG     1000
#define DIN     32
#define H1C     32
#define H2C     64
#define DEC     16
#define AAF     95
#define G_DIM   128
#define K_ST    3
#define T_L     6
#define EA_E    98
#define XDIM    159          // H2 + AAF
#define NS      21           // K + T*K weight slices
#define MPAD    64           // M padded for regular tiling
#define GP      132          // G_DIM padded
#define KP2     168          // K padded for bf16 GEMM operands
#define NSB     ((N_ATOMS + 255) / 256)   // 196 scan blocks

typedef __attribute__((ext_vector_type(8))) short bf16x8;
typedef __attribute__((ext_vector_type(4))) float f32x4;

__device__ __forceinline__ short f2bf(float f) {
    unsigned int u = __float_as_uint(f);
    unsigned int r = (u + 0x7FFFu + ((u >> 16) & 1u)) >> 16;   // RNE
    return (short)r;
}
__device__ __forceinline__ float bf2f(short b) {
    return __uint_as_float(((unsigned int)(unsigned short)b) << 16);
}

__device__ __forceinline__ void f4fma(float4& d, float s, const float4& v) {
    d.x += s * v.x; d.y += s * v.y; d.z += s * v.z; d.w += s * v.w;
}
__device__ __forceinline__ void f4add(float4& d, const float4& v) {
    d.x += v.x; d.y += v.y; d.z += v.z; d.w += v.w;
}
__device__ __forceinline__ void f4relu(float4& d) {
    d.x = fmaxf(d.x, 0.f); d.y = fmaxf(d.y, 0.f);
    d.z = fmaxf(d.z, 0.f); d.w = fmaxf(d.w, 0.f);
}

// ---------------------------------------------------------------------------
// CSR build: degree count -> 3-phase parallel scan -> bucket fill
// ---------------------------------------------------------------------------
__global__ __launch_bounds__(256) void deg_count(const int* __restrict__ eidx,
                                                 int* __restrict__ deg)
{
    int e = blockIdx.x * 256 + threadIdx.x;
    if (e >= E_EDGES) return;
    atomicAdd(&deg[eidx[E_EDGES + e]], 1);
}

__global__ __launch_bounds__(256) void scan_part(const int* __restrict__ deg,
                                                 int* __restrict__ bsum)
{
    __shared__ int tmp[256];
    int tid = threadIdx.x;
    int n = blockIdx.x * 256 + tid;
    tmp[tid] = (n < N_ATOMS) ? deg[n] : 0;
    __syncthreads();
    for (int off = 128; off > 0; off >>= 1) {
        if (tid < off) tmp[tid] += tmp[tid + off];
        __syncthreads();
    }
    if (tid == 0) bsum[blockIdx.x] = tmp[0];
}

__global__ __launch_bounds__(256) void scan_mid(const int* __restrict__ bsum,
                                                int* __restrict__ bpre)
{
    __shared__ int tmp[256];
    int tid = threadIdx.x;
    int v = (tid < NSB) ? bsum[tid] : 0;
    tmp[tid] = v;
    __syncthreads();
    for (int off = 1; off < 256; off <<= 1) {
        int t = tmp[tid];
        int add = (tid >= off) ? tmp[tid - off] : 0;
        __syncthreads();
        tmp[tid] = t + add;
        __syncthreads();
    }
    if (tid < NSB) bpre[tid] = tmp[tid] - v;   // exclusive
}

__global__ __launch_bounds__(256) void scan_out(int* __restrict__ deg_off,
                                                const int* __restrict__ bpre)
{
    __shared__ int tmp[256];
    int tid = threadIdx.x;
    int n = blockIdx.x * 256 + tid;
    int v = (n < N_ATOMS) ? deg_off[n] : 0;
    tmp[tid] = v;
    __syncthreads();
    for (int off = 1; off < 256; off <<= 1) {
        int t = tmp[tid];
        int add = (tid >= off) ? tmp[tid - off] : 0;
        __syncthreads();
        tmp[tid] = t + add;
        __syncthreads();
    }
    int incl = tmp[tid];
    int base = bpre[blockIdx.x];
    if (n < N_ATOMS) deg_off[n] = base + incl - v;
    if (n == N_ATOMS - 1) deg_off[N_ATOMS] = base + incl;
}

__global__ __launch_bounds__(256) void fill_order(const int* __restrict__ eidx,
                                                  const int* __restrict__ off,
                                                  int* __restrict__ cursor,
                                                  int* __restrict__ order)
{
    int e = blockIdx.x * 256 + threadIdx.x;
    if (e >= E_EDGES) return;
    int d = eidx[E_EDGES + e];
    int pos = atomicAdd(&cursor[d], 1);
    order[off[d] + pos] = e;
}

// ---------------------------------------------------------------------------
// MFMA edge message kernel (R16, verified).
// ---------------------------------------------------------------------------
template<int FIN, int FOUT>
__global__ __launch_bounds__(256, 2) void edge_msg_mfma(
    const float* __restrict__ h, const float* __restrict__ ea,
    const int* __restrict__ eidx, const float* __restrict__ We,
    const float* __restrict__ be, float* __restrict__ msg)
{
    static_assert(FIN == 32, "K mapping assumes FIN==32");
    constexpr int K0  = DEC * FIN;        // 512
    constexpr int KS  = (K0 + FIN) / 32;  // 17
    constexpr int WTP = 552;
    constexpr int NT  = FOUT / 16;
    __shared__ short Wt[FOUT][WTP];
    __shared__ short hA[64][40];
    __shared__ short eaA[64][16];
    int tid = threadIdx.x;
    int ebase = blockIdx.x * 64;

    for (int i = tid; i < DEC * FIN * FOUT; i += 256) {
        int o  = i % FOUT;
        int fk = i / FOUT;
        Wt[o][fk] = f2bf(We[i]);
    }
    for (int i = tid; i < FIN * FOUT; i += 256) {
        int o = i % FOUT, ff = i / FOUT;
        Wt[o][K0 + ff] = f2bf(be[i]);
    }
    for (int i = tid; i < 64 * FIN; i += 256) {
        int r = i / FIN, f = i % FIN;
        int e = ebase + r; int es = (e < E_EDGES) ? e : 0;
        int s = eidx[es];
        hA[r][f] = f2bf(h[(size_t)s * FIN + f]);
    }
    for (int i = tid; i < 64 * DEC; i += 256) {
        int r = i / DEC, d = i % DEC;
        int e = ebase + r; int es = (e < E_EDGES) ? e : 0;
        eaA[r][d] = f2bf(ea[(size_t)es * DEC + d]);
    }
    __syncthreads();

    int lane = tid & 63;
    int wave = tid >> 6;
    int l16  = lane & 15;
    int quad = lane >> 4;

    float hf[8];
    {
        const short* hp = &hA[wave * 16 + l16][quad * 8];
        #pragma unroll
        for (int j = 0; j < 8; ++j) hf[j] = bf2f(hp[j]);
    }
    float eaf[16];
    {
        const short* ep = &eaA[wave * 16 + l16][0];
        #pragma unroll
        for (int d = 0; d < 16; ++d) eaf[d] = bf2f(ep[d]);
    }

    f32x4 acc[NT];
    #pragma unroll
    for (int nt = 0; nt < NT; ++nt) acc[nt] = (f32x4){0.f, 0.f, 0.f, 0.f};

    #pragma unroll
    for (int ks = 0; ks < KS; ++ks) {
        float fac = (ks < DEC) ? eaf[ks] : 1.0f;
        bf16x8 a;
        #pragma unroll
        for (int j = 0; j < 8; ++j) a[j] = f2bf(fac * hf[j]);
        #pragma unroll
        for (int nt = 0; nt < NT; ++nt) {
            const bf16x8 b = *(const bf16x8*)&Wt[nt * 16 + l16][ks * 32 + quad * 8];
            acc[nt] = __builtin_amdgcn_mfma_f32_16x16x32_bf16(a, b, acc[nt], 0, 0, 0);
        }
    }
    #pragma unroll
    for (int nt = 0; nt < NT; ++nt) {
        #pragma unroll
        for (int r = 0; r < 4; ++r) {
            int e = ebase + wave * 16 + quad * 4 + r;
            if (e < E_EDGES)
                msg[(size_t)e * FOUT + nt * 16 + l16] = acc[nt][r];
        }
    }
}

// ---------------------------------------------------------------------------
// Gather + node update fused
// ---------------------------------------------------------------------------
template<int FIN, int FOUT>
__global__ __launch_bounds__(256) void gather_update(
    const float* __restrict__ msg, const int* __restrict__ off,
    const int* __restrict__ order, const float* __restrict__ hin,
    const float* __restrict__ root, const float* __restrict__ bias,
    float* __restrict__ hout)
{
    constexpr int NPB = 256 / FOUT;
    __shared__ float rlds[FIN][FOUT];
    __shared__ float hlds[NPB][FIN];
    int tid = threadIdx.x;
    for (int i = tid; i < FIN * FOUT / 4; i += 256) {
        *(float4*)&rlds[0][i * 4] = *(const float4*)(root + i * 4);
    }
    int nb = blockIdx.x * NPB;
    for (int i = tid; i < NPB * FIN; i += 256) {
        int ln = i / FIN, f = i % FIN;
        int n = nb + ln;
        hlds[ln][f] = (n < N_ATOMS) ? hin[(size_t)n * FIN + f] : 0.f;
    }
    __syncthreads();

    int ln = tid / FOUT, o = tid % FOUT;
    int n = nb + ln;
    if (n >= N_ATOMS) return;
    float acc = bias[o];
    #pragma unroll 8
    for (int f = 0; f < FIN; ++f) acc += hlds[ln][f] * rlds[f][o];
    int j0 = off[n], j1 = off[n + 1];
    for (int j = j0; j < j1; ++j) {
        int e = order[j];
        acc += msg[(size_t)e * FOUT + o];
    }
    hout[(size_t)n * FOUT + o] = fmaxf(acc, 0.f);
}

// ---------------------------------------------------------------------------
// Atom attention: atom_score then atom_aggregate (softmax fused in-block)
// ---------------------------------------------------------------------------
__global__ __launch_bounds__(256) void atom_score(
    const float* __restrict__ h2, const float* __restrict__ wa,
    const float* __restrict__ ba, float* __restrict__ sc)
{
    __shared__ float hl[128][65];
    int nb = blockIdx.x * 128;
    int tid = threadIdx.x;
    for (int i = tid; i < 128 * 16; i += 256) {
        int r = i >> 4, c4 = i & 15;
        int n = nb + r;
        float4 v = (n < N_ATOMS) ? *(const float4*)(h2 + (size_t)n * H2C + c4 * 4)
                                 : make_float4(0.f, 0.f, 0.f, 0.f);
        *(float4*)&hl[r][c4 * 4] = v;
    }
    __syncthreads();
    if (tid < 128) {
        int n = nb + tid;
        if (n < N_ATOMS) {
            float sv = ba[0];
            #pragma unroll 8
            for (int o = 0; o < H2C; ++o) sv += hl[tid][o] * wa[o];
            sc[n] = sv;
        }
    }
}

__global__ __launch_bounds__(256) void atom_aggregate(
    const float* __restrict__ h2, const float* __restrict__ sc,
    const int* __restrict__ labels, const float* __restrict__ aaf,
    float* __restrict__ h_aa)
{
    int bx = blockIdx.x, tid = threadIdx.x;
    if (bx < 2 * B_G) {
        __shared__ float aa8[8][M_M][32];   // 51.2 KB
        __shared__ float red[256];
        int b = bx >> 1, half = bx & 1;
        int g = tid >> 5, o = tid & 31;
        const float* sb = sc + (size_t)b * NPG;
        float lmax = -1e30f;
        for (int n = tid; n < NPG; n += 256) lmax = fmaxf(lmax, sb[n]);
        red[tid] = lmax;
        __syncthreads();
        for (int off = 128; off > 0; off >>= 1) {
            if (tid < off) red[tid] = fmaxf(red[tid], red[tid + off]);
            __syncthreads();
        }
        float mx = red[0];
        __syncthreads();
        float lsum = 0.f;
        for (int n = tid; n < NPG; n += 256) lsum += expf(sb[n] - mx);
        red[tid] = lsum;
        __syncthreads();
        for (int off = 128; off > 0; off >>= 1) {
            if (tid < off) red[tid] += red[tid + off];
            __syncthreads();
        }
        float inv = 1.f / red[0];
        __syncthreads();
        for (int i = tid; i < 8 * M_M * 32; i += 256) ((float*)aa8)[i] = 0.f;
        __syncthreads();
        const float* hb = h2 + (size_t)b * NPG * H2C + half * 32;
        for (int n = g; n < NPG; n += 8) {
            int lbl = labels[b * NPG + n];
            float w = expf(sb[n] - mx) * inv;
            float hvv = hb[(size_t)n * H2C + o];
            aa8[g][lbl][o] += hvv * w;
        }
        __syncthreads();
        float* ob = h_aa + (size_t)b * M_M * XDIM + half * 32;
        for (int i = tid; i < M_M * 32; i += 256) {
            int m = i >> 5, oo = i & 31;
            float v = 0.f;
            #pragma unroll
            for (int gg = 0; gg < 8; ++gg) v += aa8[gg][m][oo];
            ob[m * XDIM + oo] = v;
        }
    } else {
        int b = bx - 2 * B_G;
        const float* ab = aaf + (size_t)b * M_M * AAF;
        float* ob = h_aa + (size_t)b * M_M * XDIM + H2C;
        for (int i = tid; i < M_M * AAF; i += 256) {
            int m = i / AAF, j = i - m * AAF;
            ob[m * XDIM + j] = ab[i];
        }
    }
}

// ---------------------------------------------------------------------------
// Amino-graph gcn_norm + dst-sorted CSR build (tiny, 1 block)
// ---------------------------------------------------------------------------
__global__ void aa_norm_kernel(const int* __restrict__ aei,
                               int* __restrict__ aa_off,
                               int* __restrict__ aa_src,
                               float* __restrict__ aa_nrm)
{
    __shared__ int   sdeg[M_M];
    __shared__ int   scur[M_M];
    __shared__ float sdinv[M_M];
    __shared__ int   soff[M_M + 1];
    int tid = threadIdx.x;
    if (tid < M_M) { sdeg[tid] = 0; scur[tid] = 0; }
    __syncthreads();
    if (tid < EA_E) atomicAdd(&sdeg[aei[EA_E + tid]], 1);
    __syncthreads();
    if (tid < M_M) {
        float dv = (float)sdeg[tid];
        sdinv[tid] = (dv > 0.f) ? (1.f / sqrtf(fmaxf(dv, 1.f))) : 0.f;
    }
    __syncthreads();
    if (tid == 0) {
        soff[0] = 0;
        for (int m = 0; m < M_M; ++m) soff[m + 1] = soff[m] + sdeg[m];
    }
    __syncthreads();
    if (tid < EA_E) {
        int ss = aei[tid], dd = aei[EA_E + tid];
        int pos = atomicAdd(&scur[dd], 1);
        int idx = soff[dd] + pos;
        aa_src[idx] = ss;
        aa_nrm[idx] = sdinv[ss] * sdinv[dd];
    }
    if (tid < M_M + 1) aa_off[tid] = soff[tid];
}

// ---------------------------------------------------------------------------
// GEMM operand prep (bf16 transposes, all one-time / L2-hot)
// ---------------------------------------------------------------------------
__global__ __launch_bounds__(256) void prep_wt(
    const float* __restrict__ init_w, const float* __restrict__ root_w,
    short* __restrict__ Wtb)
{
    int idx = blockIdx.x * 256 + threadIdx.x;
    if (idx >= NS * XDIM * G_DIM) return;
    int s = idx / (XDIM * G_DIM);
    int rem = idx - s * XDIM * G_DIM;
    int k = rem / G_DIM, n = rem - k * G_DIM;
    float v = (s < K_ST) ? init_w[idx]
                         : root_w[(size_t)(s - K_ST) * XDIM * G_DIM + rem];
    Wtb[(size_t)s * G_DIM * KP2 + n * KP2 + k] = f2bf(v);
}

__global__ __launch_bounds__(256) void prep_aw(
    const float* __restrict__ arma_w, short* __restrict__ Wab)
{
    int idx = blockIdx.x * 256 + threadIdx.x;
    if (idx >= (T_L - 1) * K_ST * G_DIM * G_DIM) return;
    int slot = idx / (G_DIM * G_DIM);
    int rem = idx - slot * G_DIM * G_DIM;
    int p = rem / G_DIM, n = rem - p * G_DIM;   // arma_w[slot][p][n]
    Wab[(size_t)slot * G_DIM * G_DIM + n * G_DIM + p] = f2bf(arma_w[idx]);
}

__global__ __launch_bounds__(256) void prep_x0(
    const float* __restrict__ h_aa, short* __restrict__ x0b)
{
    int idx = blockIdx.x * 256 + threadIdx.x;
    if (idx >= B_G * MPAD * KP2) return;
    int b = idx / (MPAD * KP2);
    int rem = idx - b * MPAD * KP2;
    int m = rem / KP2, k = rem - m * KP2;
    float v = (m < M_M && k < XDIM) ? h_aa[((size_t)b * M_M + m) * XDIM + k] : 0.f;
    x0b[idx] = f2bf(v);
}

// ---------------------------------------------------------------------------
// MFMA rc_gemm (R20, verified): zero LDS, A/B frags from global.
// ---------------------------------------------------------------------------
__global__ __launch_bounds__(256) void rc_gemm_mfma(
    const short* __restrict__ x0b, const short* __restrict__ Wtb,
    float* __restrict__ RC)
{
    int b = blockIdx.x / NS, s = blockIdx.x % NS;
    int tid = threadIdx.x;
    int lane = tid & 63, wave = tid >> 6;
    int l16 = lane & 15, quad = lane >> 4;
    const short* xa = x0b + (size_t)b * MPAD * KP2 + (wave * 16 + l16) * KP2;
    const short* wb = Wtb + (size_t)s * G_DIM * KP2;

    f32x4 acc[8];
    #pragma unroll
    for (int nt = 0; nt < 8; ++nt) acc[nt] = (f32x4){0.f, 0.f, 0.f, 0.f};

    #pragma unroll
    for (int ks = 0; ks < 5; ++ks) {          // K = 160
        bf16x8 a = *(const bf16x8*)(xa + ks * 32 + quad * 8);
        #pragma unroll
        for (int nt = 0; nt < 8; ++nt) {
            bf16x8 bf = *(const bf16x8*)(wb + (nt * 16 + l16) * KP2 + ks * 32 + quad * 8);
            acc[nt] = __builtin_amdgcn_mfma_f32_16x16x32_bf16(a, bf, acc[nt], 0, 0, 0);
        }
    }
    float* op = RC + (size_t)(b * NS + s) * M_M * G_DIM;
    #pragma unroll
    for (int nt = 0; nt < 8; ++nt) {
        #pragma unroll
        for (int r = 0; r < 4; ++r) {
            int m = wave * 16 + quad * 4 + r;
            if (m < M_M)
                op[m * G_DIM + nt * 16 + l16] = acc[nt][r];
        }
    }
}

// ---------------------------------------------------------------------------
// ARMA recurrence, one block per (b,k), 512 threads.
// Matmul = MFMA: A from fp32 Bbuf (LDS, cvt to bf16), B from prepped global
// Wab (L2-hot), D -> Abuf. One barrier per matmul (no Wlds staging — R20's
// version spent ~18us/block on 4-way LDS bank conflicts + staging barriers).
// Prop phase uses dual-float4 cols (oi*4, 64+oi*4): 2-way banks (free).
// LDS 67.6 KB -> 2 blocks/CU co-residency.
// ---------------------------------------------------------------------------
__global__ __launch_bounds__(512) void arma_iter(
    const float* __restrict__ RC, const short* __restrict__ Wab,
    const float* __restrict__ arma_bias,
    const int* __restrict__ aa_off, const int* __restrict__ aa_src,
    const float* __restrict__ aa_nrm, float* __restrict__ gfull)
{
    __shared__ float Abuf[MPAD][GP];   // 33.8 KB
    __shared__ float Bbuf[MPAD][GP];   // 33.8 KB
    __shared__ int   s_off[M_M + 1];
    __shared__ int   s_src[EA_E];
    __shared__ float s_nrm[EA_E];
    int b = blockIdx.x / K_ST, k = blockIdx.x % K_ST;
    int tid = threadIdx.x;
    // prop mapping: cols {oi*4..+3} and {64+oi*4..+3}, rows mi*2..mi*2+1
    int oi = tid & 15, mi = tid >> 4;
    int c0 = oi * 4, c1 = 64 + oi * 4;
    // mfma mapping: 8 waves = 4 m-tiles x 2 n-halves
    int lane = tid & 63, wave = tid >> 6;
    int l16 = lane & 15, quad = lane >> 4;
    int mt = wave >> 1, nh = wave & 1;

    const float* rcb = RC + (size_t)b * NS * M_M * G_DIM;
    if (tid < M_M + 1) s_off[tid] = aa_off[tid];
    if (tid < EA_E) { s_src[tid] = aa_src[tid]; s_nrm[tid] = aa_nrm[tid]; }

    for (int i = tid; i < MPAD * G_DIM; i += 512) {
        int m = i >> 7, o = i & 127;
        Abuf[m][o] = (m < M_M) ? rcb[(size_t)k * M_M * G_DIM + i] : 0.f;
        Bbuf[m][o] = 0.f;
    }
    __syncthreads();

    for (int t = 0; t < T_L; ++t) {
        if (t > 0) {
            const short* aw = Wab + (size_t)((t - 1) * K_ST + k) * G_DIM * G_DIM;
            f32x4 acc[4];
            #pragma unroll
            for (int nt = 0; nt < 4; ++nt) acc[nt] = (f32x4){0.f, 0.f, 0.f, 0.f};
            #pragma unroll
            for (int ks = 0; ks < 4; ++ks) {       // K = 128
                bf16x8 a;
                const float* ap = &Bbuf[mt * 16 + l16][ks * 32 + quad * 8];
                #pragma unroll
                for (int j = 0; j < 8; ++j) a[j] = f2bf(ap[j]);
                #pragma unroll
                for (int nt = 0; nt < 4; ++nt) {
                    int n0 = (nh * 4 + nt) * 16 + l16;
                    bf16x8 bf = *(const bf16x8*)(aw + n0 * G_DIM + ks * 32 + quad * 8);
                    acc[nt] = __builtin_amdgcn_mfma_f32_16x16x32_bf16(a, bf, acc[nt], 0, 0, 0);
                }
            }
            // D -> Abuf (C-layout: row = mt*16+quad*4+r, col = (nh*4+nt)*16+l16)
            #pragma unroll
            for (int nt = 0; nt < 4; ++nt) {
                #pragma unroll
                for (int r = 0; r < 4; ++r) {
                    Abuf[mt * 16 + quad * 4 + r][(nh * 4 + nt) * 16 + l16] = acc[nt][r];
                }
            }
            __syncthreads();   // Abuf complete before prop reads
        }
        const float* rct = rcb + (size_t)(K_ST + t * K_ST + k) * M_M * G_DIM;
        const float* bb  = arma_bias + ((size_t)t * K_ST + k) * G_DIM;
        float4 bias0 = *(const float4*)(bb + c0);
        float4 bias1 = *(const float4*)(bb + c1);
        #pragma unroll
        for (int r = 0; r < 2; ++r) {
            int m = mi * 2 + r;
            if (m < M_M) {
                const float* rr = rct + (size_t)m * G_DIM;
                float4 v0 = bias0, v1 = bias1;
                f4add(v0, *(const float4*)(rr + c0));
                f4add(v1, *(const float4*)(rr + c1));
                int j0 = s_off[m], j1 = s_off[m + 1];
                for (int j = j0; j < j1; ++j) {
                    float nv = s_nrm[j];
                    const float* ap = &Abuf[s_src[j]][0];
                    f4fma(v0, nv, *(const float4*)(ap + c0));
                    f4fma(v1, nv, *(const float4*)(ap + c1));
                }
                f4relu(v0);
                f4relu(v1);
                *(float4*)&Bbuf[m][c0] = v0;
                *(float4*)&Bbuf[m][c1] = v1;
            }
        }
        __syncthreads();   // Bbuf (state) complete; Abuf reads done
    }
    float* gb = gfull + ((size_t)(b * K_ST + k)) * M_M * G_DIM;
    for (int i = tid; i < M_M * G_DIM; i += 512) {
        int m = i >> 7, o = i & 127;
        gb[i] = Bbuf[m][o];
    }
}

// ---------------------------------------------------------------------------
// Mean over K, amino attention readout, MLP head. One block per graph.
// ---------------------------------------------------------------------------
__global__ __launch_bounds__(128) void aa_readout_mlp(
    const float* __restrict__ gfull, const float* __restrict__ wa,
    const float* __restrict__ ba,
    const float* __restrict__ W1, const float* __restrict__ b1,
    const float* __restrict__ W2, const float* __restrict__ b2,
    const float* __restrict__ W3, const float* __restrict__ b3,
    const float* __restrict__ W4, const float* __restrict__ b4,
    float* __restrict__ out)
{
    __shared__ float g[M_M][G_DIM + 1];
    __shared__ float s2[M_M];
    __shared__ float p[G_DIM];
    __shared__ float r1[64], r2[32], r3[16];
    int b = blockIdx.x, tid = threadIdx.x;
    const float* g0 = gfull + (size_t)b * K_ST * M_M * G_DIM;
    for (int i = tid; i < M_M * G_DIM; i += 128) {
        int m = i >> 7, o = i & 127;
        g[m][o] = (g0[i] + g0[M_M*G_DIM + i] + g0[2*M_M*G_DIM + i]) * (1.f/3.f);
    }
    __syncthreads();
    if (tid < M_M) {
        float sv = ba[0];
        for (int o = 0; o < G_DIM; ++o) sv += g[tid][o] * wa[o];
        s2[tid] = sv;
    }
    __syncthreads();
    if (tid == 0) {
        float mx = -1e30f;
        for (int m = 0; m < M_M; ++m) mx = fmaxf(mx, s2[m]);
        float den = 0.f;
        for (int m = 0; m < M_M; ++m) den += expf(s2[m] - mx);
        float inv = 1.f / den;
        for (int m = 0; m < M_M; ++m) s2[m] = expf(s2[m] - mx) * inv;
    }
    __syncthreads();
    {
        float pv = 0.f;
        for (int m = 0; m < M_M; ++m) pv += g[m][tid] * s2[m];
        p[tid] = pv;
    }
    __syncthreads();
    if (tid < 64) {
        float v = b1[tid];
        for (int i = 0; i < 128; ++i) v += p[i] * W1[i * 64 + tid];
        r1[tid] = fmaxf(v, 0.f);
    }
    __syncthreads();
    if (tid < 32) {
        float v = b2[tid];
        for (int i = 0; i < 64; ++i) v += r1[i] * W2[i * 32 + tid];
        r2[tid] = fmaxf(v, 0.f);
    }
    __syncthreads();
    if (tid < 16) {
        float v = b3[tid];
        for (int i = 0; i < 32; ++i) v += r2[i] * W3[i * 16 + tid];
        r3[tid] = fmaxf(v, 0.f);
    }
    __syncthreads();
    if (tid == 0) {
        float v = b4[0];
        for (int i = 0; i < 16; ++i) v += r3[i] * W4[i];
        out[b] = v;
    }
}

// ---------------------------------------------------------------------------
extern "C" void kernel_launch(void* const* d_in, const int* in_sizes, int n_in,
                              void* d_out, int out_size, void* d_ws, size_t ws_size,
                              hipStream_t stream)
{
    (void)in_sizes; (void)n_in; (void)out_size; (void)ws_size;
    const float* x            = (const float*)d_in[0];
    const float* edge_attr    = (const float*)d_in[1];
    const float* aa_features  = (const float*)d_in[2];
    const int*   edge_index   = (const int*)  d_in[3];
    const int*   mono_labels  = (const int*)  d_in[4];
    const int*   amino_ei     = (const int*)  d_in[5];
    const float* W_e1 = (const float*)d_in[6];
    const float* b_e1 = (const float*)d_in[7];
    const float* root1= (const float*)d_in[8];
    const float* bias1= (const float*)d_in[9];
    const float* W_e2 = (const float*)d_in[10];
    const float* b_e2 = (const float*)d_in[11];
    const float* root2= (const float*)d_in[12];
    const float* bias2= (const float*)d_in[13];
    const float* Wa_atom = (const float*)d_in[14];
    const float* ba_atom = (const float*)d_in[15];
    const float* arma_init_w = (const float*)d_in[16];
    const float* arma_w      = (const float*)d_in[17];
    const float* arma_root_w = (const float*)d_in[18];
    const float* arma_bias   = (const float*)d_in[19];
    const float* Wa_aa = (const float*)d_in[20];
    const float* ba_aa = (const float*)d_in[21];
    const float* W1 = (const float*)d_in[22];
    const float* b1 = (const float*)d_in[23];
    const float* W2 = (const float*)d_in[24];
    const float* b2 = (const float*)d_in[25];
    const float* W3 = (const float*)d_in[26];
    const float* b3 = (const float*)d_in[27];
    const float* W4 = (const float*)d_in[28];
    const float* b4 = (const float*)d_in[29];

    float* ws = (float*)d_ws;
    float* h1    = ws;                                   // N*32
    float* h2    = h1   + (size_t)N_ATOMS * H1C;         // N*64
    float* h_aa  = h2   + (size_t)N_ATOMS * H2C;         // B*M*159
    float* sc    = h_aa + (size_t)B_G * M_M * XDIM;      // B*NPG (scores)
    int*   aa_off = (int*)(sc + (size_t)B_G * NPG);      // M+1
    int*   aa_src = aa_off + (M_M + 1);                  // EA
    float* aa_nrm = (float*)(aa_src + EA_E);             // EA
    int*   deg_off = (int*)(aa_nrm + EA_E);              // N+1
    int*   cursor  = deg_off + (N_ATOMS + 1);            // N (adjacent -> one memset)
    int*   order   = cursor + N_ATOMS;                   // E
    int*   bsum    = order + E_EDGES;                    // NSB
    int*   bpre    = bsum + 256;                         // NSB
    float* RC    = (float*)(bpre + 256);                 // B*21*M*128 (26.9 MB)
    float* gfull = RC + (size_t)B_G * NS * M_M * G_DIM;  // B*3*M*128
    short* Wtb   = (short*)((((uintptr_t)(gfull + (size_t)B_G * K_ST * M_M * G_DIM)) + 15)
                            & ~(uintptr_t)15);           // NS*128*168 bf16 (903 KB)
    short* x0b   = Wtb + (size_t)NS * G_DIM * KP2;       // B*64*168 bf16 (1.07 MB)
    short* Wab   = x0b + (size_t)B_G * MPAD * KP2;       // 15*128*128 bf16 (492 KB)
    float* msg   = RC;   // alias: msg dead before rc_gemm writes RC

    (void)hipMemsetAsync(deg_off, 0, (2 * N_ATOMS + 1) * sizeof(int), stream);

    int eblocks = (E_EDGES + 255) / 256;
    int mblocks = (E_EDGES + 63) / 64;    // MFMA edge kernels: 64 edges/block

    // CSR build (3-phase parallel scan)
    deg_count<<<eblocks, 256, 0, stream>>>(edge_index, deg_off);
    scan_part<<<NSB, 256, 0, stream>>>(deg_off, bsum);
    scan_mid<<<1, 256, 0, stream>>>(bsum, bpre);
    scan_out<<<NSB, 256, 0, stream>>>(deg_off, bpre);
    fill_order<<<eblocks, 256, 0, stream>>>(edge_index, deg_off, cursor, order);

    // W prep (independent of the pipeline above)
    prep_wt<<<(NS * XDIM * G_DIM + 255) / 256, 256, 0, stream>>>(
        arma_init_w, arma_root_w, Wtb);
    prep_aw<<<((T_L - 1) * K_ST * G_DIM * G_DIM + 255) / 256, 256, 0, stream>>>(
        arma_w, Wab);

    // conv1 (MFMA, bf16 inputs / fp32 accumulate)
    edge_msg_mfma<DIN, H1C><<<mblocks, 256, 0, stream>>>(
        x, edge_attr, edge_index, W_e1, b_e1, msg);
    gather_update<DIN, H1C><<<(N_ATOMS + 7) / 8, 256, 0, stream>>>(
        msg, deg_off, order, x, root1, bias1, h1);
    // conv2 (MFMA)
    edge_msg_mfma<H1C, H2C><<<mblocks, 256, 0, stream>>>(
        h1, edge_attr, edge_index, W_e2, b_e2, msg);
    gather_update<H1C, H2C><<<(N_ATOMS + 3) / 4, 256, 0, stream>>>(
        msg, deg_off, order, h1, root2, bias2, h2);

    // atom attention readout (softmax fused into aggregate)
    atom_score<<<(N_ATOMS + 127) / 128, 256, 0, stream>>>(h2, Wa_atom, ba_atom, sc);
    atom_aggregate<<<3 * B_G, 256, 0, stream>>>(h2, sc, mono_labels, aa_features, h_aa);

    aa_norm_kernel<<<1, 128, 0, stream>>>(amino_ei, aa_off, aa_src, aa_nrm);
    prep_x0<<<(B_G * MPAD * KP2 + 255) / 256, 256, 0, stream>>>(h_aa, x0b);
    rc_gemm_mfma<<<B_G * NS, 256, 0, stream>>>(x0b, Wtb, RC);
    arma_iter<<<B_G * K_ST, 512, 0, stream>>>(RC, Wab, arma_bias,
                                              aa_off, aa_src, aa_nrm, gfull);
    aa_readout_mlp<<<B_G, 128, 0, stream>>>(gfull, Wa_aa, ba_aa, W1, b1, W2, b2, W3, b3, W4, b4,
                                            (float*)d_out);
}